// Round 1
// baseline (640.931 us; speedup 1.0000x reference)
//
#include <hip/hip_runtime.h>
#include <stdint.h>

#define Bv 2
#define Cv 256
#define Nv 4096
#define NHv 4
#define HDv 64
#define Kv 16

// R7: attn rewritten barrier-free: 16-row q-tiles, 2048 blocks, in-block
// split-m x4 (wave-strided K/V tiles), direct-global K/V fragments (L2/LLC
// resident), LDS-atomic combine -> aob written directly (opart/lpart/combine_k
// deleted). exp2-domain softmax (log2e folded into q scale). MLP GEMMs moved
// to 64x64 tiles (1024/512 blocks instead of 256/128).

typedef __attribute__((ext_vector_type(8))) short bf16x8;
typedef __attribute__((ext_vector_type(4))) float f32x4;

__device__ __forceinline__ float bf2f(unsigned short u) {
  union { unsigned int i; float f; } x; x.i = ((unsigned int)u) << 16; return x.f;
}
__device__ __forceinline__ unsigned short f2bf(float f) {
  union { float f; unsigned int i; } x; x.f = f;
  unsigned int r = x.i + 0x7FFF + ((x.i >> 16) & 1);   // RNE
  return (unsigned short)(r >> 16);
}

// ---------------------------------------------------------------------------
// Prep 1: img [b][c][n] fp32 -> imgT [z][n][c] bf16  (z = img*2 + b, z<6)
// ---------------------------------------------------------------------------
__global__ __launch_bounds__(256) void imgt_k(
    const float* __restrict__ qi, const float* __restrict__ ki,
    const float* __restrict__ vi, unsigned short* __restrict__ dst)
{
  const int z = blockIdx.z;
  const float* src = (z < 2 ? qi : (z < 4 ? ki : vi)) + (long long)(z & 1) * Cv * Nv;
  unsigned short* out = dst + (long long)z * Nv * Cv;
  __shared__ float t[32][33];
  const int x = threadIdx.x, y = threadIdx.y;
  const int n0 = blockIdx.x * 32, c0 = blockIdx.y * 32;
  for (int i = y; i < 32; i += 8)
    t[i][x] = src[(long long)(c0 + i) * Nv + n0 + x];
  __syncthreads();
  for (int i = y; i < 32; i += 8)
    out[(long long)(n0 + i) * Cv + c0 + x] = f2bf(t[x][i]);
}

// ---------------------------------------------------------------------------
// Prep 2: W [k][n] fp32 -> Wt [n][k] bf16, 7 weights packed into one buffer
// ---------------------------------------------------------------------------
struct WP { const float* p[7]; };

__global__ __launch_bounds__(256) void wt_k(WP wp, unsigned short* __restrict__ dst)
{
  const int z = blockIdx.z;
  const int KD[7] = {256, 256, 256, 256, 512, 256, 512};
  const int ND[7] = {256, 256, 256, 512, 256, 512, 256};
  const long long OFF[7] = {0, 65536, 131072, 196608, 327680, 458752, 589824};
  const int Kw = KD[z], Nw = ND[z];
  const int nb = blockIdx.x * 32, kb2 = blockIdx.y * 32;
  if (nb >= Nw || kb2 >= Kw) return;
  __shared__ float t[32][33];
  const int x = threadIdx.x, y = threadIdx.y;
  const float* src = wp.p[z];
  for (int i = y; i < 32; i += 8)
    t[i][x] = src[(long long)(kb2 + i) * Nw + nb + x];
  __syncthreads();
  for (int i = y; i < 32; i += 8)
    dst[OFF[z] + (long long)(nb + i) * Kw + kb2 + x] = f2bf(t[x][i]);
}

// ---------------------------------------------------------------------------
// Fused q/k/v projection: one dispatch, z = proj*2 + b (z<6).
// 128x128 tile, BK=64. Epilogue per proj: q->qbf(*0.125*log2e), k->kbf,
// v->vpp fp32 + vtb bf16 transposed [c][n].
// ---------------------------------------------------------------------------
__global__ __launch_bounds__(256) void proj_k(
    const unsigned short* __restrict__ imgT, const unsigned short* __restrict__ wt,
    const float* __restrict__ bq, const float* __restrict__ bk, const float* __restrict__ bv,
    unsigned short* __restrict__ qbf, unsigned short* __restrict__ kbf,
    float* __restrict__ vpp, unsigned short* __restrict__ vtb)
{
  __shared__ __align__(16) unsigned short As[128][72];
  __shared__ __align__(16) unsigned short Bs[128][72];
  const int tid = threadIdx.x;
  const int w = tid >> 6, lane = tid & 63;
  const int lr = lane & 15, quad = lane >> 4;
  const int m0 = blockIdx.x * 128, n0 = blockIdx.y * 128;
  const int z = blockIdx.z, zz = z >> 1, bb = z & 1;
  const int wm = (w >> 1) * 64, wn = (w & 1) * 64;
  const int sr = tid >> 1, sh = (tid & 1) * 32;
  const long long NvCv = (long long)Nv * Cv;

  const float* bias = zz == 0 ? bq : (zz == 1 ? bk : bv);
  const unsigned short* Ab0 = imgT + (long long)z * NvCv + (long long)(m0 + sr) * Cv + sh;
  const unsigned short* Bb0 = wt + (long long)zz * 65536 + (long long)(n0 + sr) * Cv + sh;

  f32x4 acc[4][4];
#pragma unroll
  for (int i = 0; i < 4; ++i)
#pragma unroll
    for (int j = 0; j < 4; ++j) acc[i][j] = (f32x4){0.f, 0.f, 0.f, 0.f};

  for (int k0 = 0; k0 < Cv; k0 += 64) {
    const unsigned short* Ab = Ab0 + k0;
    const unsigned short* Bp = Bb0 + k0;
    uint4 a0 = *(const uint4*)Ab, a1 = *(const uint4*)(Ab + 8);
    uint4 a2 = *(const uint4*)(Ab + 16), a3 = *(const uint4*)(Ab + 24);
    uint4 b0 = *(const uint4*)Bp, b1 = *(const uint4*)(Bp + 8);
    uint4 b2 = *(const uint4*)(Bp + 16), b3 = *(const uint4*)(Bp + 24);
    *(uint4*)&As[sr][sh] = a0; *(uint4*)&As[sr][sh + 8] = a1;
    *(uint4*)&As[sr][sh + 16] = a2; *(uint4*)&As[sr][sh + 24] = a3;
    *(uint4*)&Bs[sr][sh] = b0; *(uint4*)&Bs[sr][sh + 8] = b1;
    *(uint4*)&Bs[sr][sh + 16] = b2; *(uint4*)&Bs[sr][sh + 24] = b3;
    __syncthreads();
#pragma unroll
    for (int ks = 0; ks < 2; ++ks) {
      bf16x8 af[4], bfr[4];
#pragma unroll
      for (int i = 0; i < 4; ++i)
        af[i] = *(const bf16x8*)&As[wm + i * 16 + lr][ks * 32 + quad * 8];
#pragma unroll
      for (int j = 0; j < 4; ++j)
        bfr[j] = *(const bf16x8*)&Bs[wn + j * 16 + lr][ks * 32 + quad * 8];
#pragma unroll
      for (int i = 0; i < 4; ++i)
#pragma unroll
        for (int j = 0; j < 4; ++j)
          acc[i][j] = __builtin_amdgcn_mfma_f32_16x16x32_bf16(af[i], bfr[j], acc[i][j], 0, 0, 0);
    }
    __syncthreads();
  }

#pragma unroll
  for (int j = 0; j < 4; ++j) {
    const int col = n0 + wn + j * 16 + lr;
    const float bvv = bias[col];
#pragma unroll
    for (int i = 0; i < 4; ++i) {
      const int mb = m0 + wm + i * 16 + quad * 4;
      float r[4];
#pragma unroll
      for (int reg = 0; reg < 4; ++reg) r[reg] = acc[i][j][reg] + bvv;
      const long long ob = (long long)bb * NvCv;
      if (zz == 0) {
        // 0.125 (1/SCALE) * log2(e): softmax runs in exp2 domain
#pragma unroll
        for (int reg = 0; reg < 4; ++reg)
          qbf[ob + (long long)(mb + reg) * Cv + col] = f2bf(r[reg] * 0.18033688f);
      } else if (zz == 1) {
#pragma unroll
        for (int reg = 0; reg < 4; ++reg)
          kbf[ob + (long long)(mb + reg) * Cv + col] = f2bf(r[reg]);
      } else {
#pragma unroll
        for (int reg = 0; reg < 4; ++reg)
          vpp[ob + (long long)(mb + reg) * Cv + col] = r[reg];
        uint2 pk;
        pk.x = f2bf(r[0]) | ((unsigned int)f2bf(r[1]) << 16);
        pk.y = f2bf(r[2]) | ((unsigned int)f2bf(r[3]) << 16);
        *(uint2*)&vtb[ob + (long long)col * Nv + mb] = pk;
      }
    }
  }
}

// ---------------------------------------------------------------------------
// 64x64-tile bf16 MFMA GEMM for the MLPs. 4 waves in 2x2, each 32x32.
// OM: 0 fp32 [m][n]; 1 bf16 [m][n]; 4 fp32 transposed to [B][C][N].
// ---------------------------------------------------------------------------
template<bool ABF16, int ACT, int RES, int OM>
__global__ __launch_bounds__(256) void mm64_k(
    const void* __restrict__ A, const unsigned short* __restrict__ Bt,
    const float* __restrict__ bias, const float* __restrict__ Res,
    float* __restrict__ outF, unsigned short* __restrict__ outB,
    int M, int Nn, int Kd)
{
  __shared__ __align__(16) unsigned short As[64][72];
  __shared__ __align__(16) unsigned short Bs[64][72];
  const int tid = threadIdx.x;
  const int w = tid >> 6, lane = tid & 63;
  const int lr = lane & 15, quad = lane >> 4;
  const int m0 = blockIdx.x * 64, n0 = blockIdx.y * 64;
  const int wm = (w >> 1) * 32, wn = (w & 1) * 32;
  const int sr = tid >> 2, sh = (tid & 3) * 16;

  f32x4 acc[2][2];
#pragma unroll
  for (int i = 0; i < 2; ++i)
#pragma unroll
    for (int j = 0; j < 2; ++j) acc[i][j] = (f32x4){0.f, 0.f, 0.f, 0.f};

  const long long abase = (long long)(m0 + sr) * Kd + sh;
  const unsigned short* Bb = Bt + (long long)(n0 + sr) * Kd + sh;

  for (int k0 = 0; k0 < Kd; k0 += 64) {
    if (ABF16) {
      const unsigned short* Ab = (const unsigned short*)A + abase + k0;
      uint4 u0 = *(const uint4*)Ab, u1 = *(const uint4*)(Ab + 8);
      *(uint4*)&As[sr][sh] = u0; *(uint4*)&As[sr][sh + 8] = u1;
    } else {
      const float* Af = (const float*)A + abase + k0;
#pragma unroll
      for (int t = 0; t < 2; ++t) {
        const float4 f0 = *(const float4*)(Af + t * 8);
        const float4 f1 = *(const float4*)(Af + t * 8 + 4);
        uint4 pk;
        pk.x = f2bf(f0.x) | ((unsigned int)f2bf(f0.y) << 16);
        pk.y = f2bf(f0.z) | ((unsigned int)f2bf(f0.w) << 16);
        pk.z = f2bf(f1.x) | ((unsigned int)f2bf(f1.y) << 16);
        pk.w = f2bf(f1.z) | ((unsigned int)f2bf(f1.w) << 16);
        *(uint4*)&As[sr][sh + t * 8] = pk;
      }
    }
    {
      const unsigned short* Bp = Bb + k0;
      uint4 u0 = *(const uint4*)Bp, u1 = *(const uint4*)(Bp + 8);
      *(uint4*)&Bs[sr][sh] = u0; *(uint4*)&Bs[sr][sh + 8] = u1;
    }
    __syncthreads();
#pragma unroll
    for (int ks = 0; ks < 2; ++ks) {
      bf16x8 af[2], bfr[2];
#pragma unroll
      for (int i = 0; i < 2; ++i)
        af[i] = *(const bf16x8*)&As[wm + i * 16 + lr][ks * 32 + quad * 8];
#pragma unroll
      for (int j = 0; j < 2; ++j)
        bfr[j] = *(const bf16x8*)&Bs[wn + j * 16 + lr][ks * 32 + quad * 8];
#pragma unroll
      for (int i = 0; i < 2; ++i)
#pragma unroll
        for (int j = 0; j < 2; ++j)
          acc[i][j] = __builtin_amdgcn_mfma_f32_16x16x32_bf16(af[i], bfr[j], acc[i][j], 0, 0, 0);
    }
    __syncthreads();
  }

#pragma unroll
  for (int j = 0; j < 2; ++j) {
    const int col = n0 + wn + j * 16 + lr;
    const float bv = bias[col];
#pragma unroll
    for (int i = 0; i < 2; ++i) {
      const int mb = m0 + wm + i * 16 + quad * 4;
      float r[4];
#pragma unroll
      for (int reg = 0; reg < 4; ++reg) {
        float v = acc[i][j][reg] + bv;
        if (ACT) v = v > 0.f ? v : 0.01f * v;
        if (RES) v += Res[(long long)(mb + reg) * Nn + col];
        r[reg] = v;
      }
      if (OM == 0) {
#pragma unroll
        for (int reg = 0; reg < 4; ++reg)
          outF[(long long)(mb + reg) * Nn + col] = r[reg];
      } else if (OM == 1) {
#pragma unroll
        for (int reg = 0; reg < 4; ++reg)
          outB[(long long)(mb + reg) * Nn + col] = f2bf(r[reg]);
      } else {  // OM == 4: fp32 [B][C][N], m flattened over (b,n)
        const float4 st = {r[0], r[1], r[2], r[3]};
        *(float4*)&outF[((long long)((mb >> 12) * Cv + col)) * Nv + (mb & 4095)] = st;
      }
    }
  }
}

// ---------------------------------------------------------------------------
// Cluster centers
// ---------------------------------------------------------------------------
__global__ __launch_bounds__(256) void zero_k(float* p, int n)
{
  const int i = blockIdx.x * 256 + threadIdx.x;
  if (i < n) p[i] = 0.f;
}

__global__ __launch_bounds__(256) void center_accum(
    const unsigned short* __restrict__ kb, const int* __restrict__ labels,
    float* __restrict__ cent, float* __restrict__ cnts)
{
  __shared__ int lab_s[512];
  const int bx = blockIdx.x;           // Bv*Kv*8 blocks
  const int chunk = bx & 7;
  const int kk = (bx >> 3) & 15;
  const int b = bx >> 7;
  const int c = threadIdx.x;
  const int nbase = chunk * 512;
  for (int i = threadIdx.x; i < 512; i += 256) lab_s[i] = labels[b * Nv + nbase + i];
  __syncthreads();
  float acc = 0.f;
  int cnt = 0;
#pragma unroll 4
  for (int i = 0; i < 512; ++i) {
    if (lab_s[i] == kk) {              // wave-uniform branch on LDS value
      acc += bf2f(kb[(long long)(b * Nv + nbase + i) * Cv + c]);
      ++cnt;
    }
  }
  atomicAdd(&cent[(b * Kv + kk) * Cv + c], acc);
  if (c == 0) atomicAdd(&cnts[b * Kv + kk], (float)cnt);
}

__global__ __launch_bounds__(256) void center_norm(float* cent, const float* cnts)
{
  const int i = blockIdx.x * 256 + threadIdx.x;  // Bv*Kv*Cv
  cent[i] = cent[i] / (cnts[i >> 8] + 1e-6f);
}

// ---------------------------------------------------------------------------
// Barrier-free MFMA flash attention. Block = (b, qt, h): 16 q-rows, one head.
// 4 waves split the m-dimension (wave w takes 64-tiles w, w+4, ..., 16 each).
// K/V fragments loaded directly from global (L2/LLC-resident, full-line use).
// P round-trips per-wave LDS (same-wave in-order, no barrier). Partials
// combined in-block via LDS f32 atomics; writes aob (bf16) directly.
// exp2-domain: q pre-scaled by 0.125*log2e, p = exp2(s' - 4*log2e).
// ---------------------------------------------------------------------------
__global__ __launch_bounds__(256) void attn_k(
    const unsigned short* __restrict__ qb, const unsigned short* __restrict__ kb,
    const unsigned short* __restrict__ vtb, const float* __restrict__ cent,
    const int* __restrict__ labels, const float* __restrict__ pc,
    unsigned short* __restrict__ aob)
{
  __shared__ __align__(16) unsigned short p_s[4][16][68];  // per-wave P tile
  __shared__ float ac_s[16][17];                           // q_r . center_k
  __shared__ float combO[16][68];                          // cross-wave O sum
  __shared__ float combL[16];                              // cross-wave l sum

  const int tid = threadIdx.x;
  const int lane = tid & 63, w = tid >> 6;
  const int lr = lane & 15, quad = lane >> 4;
  const int bx = blockIdx.x;
  const int h = bx & 3, qt = (bx >> 2) & 255, b = bx >> 10;
  const int n0 = qt * 16;
  const int row4 = quad * 4;

  // q fragments (16 rows, this head's 64 channels), direct from global
  const unsigned short* qp = qb + ((long long)(b * Nv + n0 + lr)) * Cv + h * HDv + quad * 8;
  const bf16x8 qa0 = *(const bf16x8*)qp;
  const bf16x8 qa1 = *(const bf16x8*)(qp + 32);

  // per-wave persistent pointers (wave w owns m-tiles w*64 + tt*256)
  const unsigned short* kwp = kb + ((long long)(b * Nv + w * 64 + lr)) * Cv + h * HDv + quad * 8;
  const unsigned short* vwp = vtb + ((long long)(b * Cv + h * HDv + lr)) * Nv + w * 64 + quad * 8;
  const float* pcw = pc + (long long)b * Nv * Nv + (long long)(n0 + row4) * Nv + w * 64 + lr;
  const int* lbw = labels + b * Nv + w * 64 + lr;

  // ac_s[r][k] = q_r . center_k (f32; q carries 0.125*log2e scale)
  {
    const int r = tid >> 4, kk = tid & 15;
    const unsigned short* qr = qb + ((long long)(b * Nv + n0 + r)) * Cv + h * HDv;
    const float* cr = cent + ((long long)(b * Kv + kk)) * Cv + h * HDv;
    float s0 = 0.f, s1 = 0.f, s2 = 0.f, s3 = 0.f;
#pragma unroll
    for (int d = 0; d < HDv; d += 4) {
      s0 += bf2f(qr[d]) * cr[d];
      s1 += bf2f(qr[d + 1]) * cr[d + 1];
      s2 += bf2f(qr[d + 2]) * cr[d + 2];
      s3 += bf2f(qr[d + 3]) * cr[d + 3];
    }
    ac_s[r][kk] = (s0 + s1) + (s2 + s3);
  }

  int labq[4];
#pragma unroll
  for (int reg = 0; reg < 4; ++reg) labq[reg] = labels[b * Nv + n0 + row4 + reg];

  // prefetch tile-0 pc/labels (in flight across the barrier)
  float pcv[4][4];
  int labm[4];
#pragma unroll
  for (int sub = 0; sub < 4; ++sub) {
    labm[sub] = lbw[sub * 16];
#pragma unroll
    for (int reg = 0; reg < 4; ++reg)
      pcv[sub][reg] = pcw[(long long)reg * Nv + sub * 16];
  }

  __syncthreads();               // ac_s visible; only barrier before epilogue

  f32x4 oacc[4];
#pragma unroll
  for (int s2 = 0; s2 < 4; ++s2) oacc[s2] = (f32x4){0.f, 0.f, 0.f, 0.f};
  float lrow[4] = {0.f, 0.f, 0.f, 0.f};

  for (int tt = 0; tt < 16; ++tt) {
    const unsigned short* kt = kwp + (long long)tt * (256 * Cv);
    const unsigned short* vt = vwp + tt * 256;

    // QK^T (K fragments direct from global)
    f32x4 sacc[4];
#pragma unroll
    for (int sub = 0; sub < 4; ++sub) {
      const bf16x8 k0v = *(const bf16x8*)(kt + sub * (16 * Cv));
      const bf16x8 k1v = *(const bf16x8*)(kt + sub * (16 * Cv) + 32);
      f32x4 s = (f32x4){0.f, 0.f, 0.f, 0.f};
      s = __builtin_amdgcn_mfma_f32_16x16x32_bf16(qa0, k0v, s, 0, 0, 0);
      s = __builtin_amdgcn_mfma_f32_16x16x32_bf16(qa1, k1v, s, 0, 0, 0);
      sacc[sub] = s;
    }

    // adaptive select + exp2(s - 4*log2e), accumulate denominator
#pragma unroll
    for (int reg = 0; reg < 4; ++reg) {
      const int Ln = labq[reg];
#pragma unroll
      for (int sub = 0; sub < 4; ++sub) {
        const float s = (labm[sub] == Ln) ? sacc[sub][reg]
                                          : ac_s[row4 + reg][labm[sub]] * pcv[sub][reg];
        const float p = exp2f(s - 5.770780f);
        lrow[reg] += p;
        p_s[w][row4 + reg][sub * 16 + lr] = f2bf(p);
      }
    }

    // pc/labels consumed -> issue next tile's (hides HBM under PV + next QK)
    if (tt < 15) {
      const int off = (tt + 1) * 256;
#pragma unroll
      for (int sub = 0; sub < 4; ++sub) {
        labm[sub] = lbw[off + sub * 16];
#pragma unroll
        for (int reg = 0; reg < 4; ++reg)
          pcv[sub][reg] = pcw[(long long)reg * Nv + off + sub * 16];
      }
    }

    // PV (P same-wave LDS in-order; V fragments direct from global)
    const bf16x8 pa0 = *(const bf16x8*)&p_s[w][lr][quad * 8];
    const bf16x8 pa1 = *(const bf16x8*)&p_s[w][lr][32 + quad * 8];
#pragma unroll
    for (int sub = 0; sub < 4; ++sub) {
      const bf16x8 v0v = *(const bf16x8*)(vt + (long long)sub * (16 * Nv));
      const bf16x8 v1v = *(const bf16x8*)(vt + (long long)sub * (16 * Nv) + 32);
      oacc[sub] = __builtin_amdgcn_mfma_f32_16x16x32_bf16(pa0, v0v, oacc[sub], 0, 0, 0);
      oacc[sub] = __builtin_amdgcn_mfma_f32_16x16x32_bf16(pa1, v1v, oacc[sub], 0, 0, 0);
    }
  }

  // reduce lrow over the 16-lane group (lanes with same quad share rows)
#pragma unroll
  for (int reg = 0; reg < 4; ++reg) {
    lrow[reg] += __shfl_xor(lrow[reg], 1);
    lrow[reg] += __shfl_xor(lrow[reg], 2);
    lrow[reg] += __shfl_xor(lrow[reg], 4);
    lrow[reg] += __shfl_xor(lrow[reg], 8);
  }

  // in-block combine of the 4 m-partials via LDS atomics
  for (int i = tid; i < 16 * 68; i += 256) (&combO[0][0])[i] = 0.f;
  if (tid < 16) combL[tid] = 0.f;
  __syncthreads();
#pragma unroll
  for (int sub = 0; sub < 4; ++sub)
#pragma unroll
    for (int reg = 0; reg < 4; ++reg)
      atomicAdd(&combO[row4 + reg][sub * 16 + lr], oacc[sub][reg]);
  if (lr == 0) {
#pragma unroll
    for (int reg = 0; reg < 4; ++reg) atomicAdd(&combL[row4 + reg], lrow[reg]);
  }
  __syncthreads();

  // normalize + write bf16 output: thread -> (row, 4 cols)
  {
    const int row = tid >> 4, c4 = (tid & 15) * 4;
    const float inv = 1.f / combL[row];
    const float o0 = combO[row][c4] * inv, o1 = combO[row][c4 + 1] * inv;
    const float o2 = combO[row][c4 + 2] * inv, o3 = combO[row][c4 + 3] * inv;
    uint2 pk;
    pk.x = f2bf(o0) | ((unsigned int)f2bf(o1) << 16);
    pk.y = f2bf(o2) | ((unsigned int)f2bf(o3) << 16);
    *(uint2*)&aob[((long long)(b * Nv + n0 + row)) * Cv + h * HDv + c4] = pk;
  }
}

// ---------------------------------------------------------------------------
extern "C" void kernel_launch(void* const* d_in, const int* in_sizes, int n_in,
                              void* d_out, int out_size, void* d_ws, size_t ws_size,
                              hipStream_t stream)
{
  const float* q_img = (const float*)d_in[0];
  const float* k_img = (const float*)d_in[1];
  const float* v_img = (const float*)d_in[2];
  const int* labels  = (const int*)d_in[3];
  const float* pc    = (const float*)d_in[4];
  const float* Wq  = (const float*)d_in[5];  const float* bq  = (const float*)d_in[6];
  const float* Wk  = (const float*)d_in[7];  const float* bk  = (const float*)d_in[8];
  const float* Wv  = (const float*)d_in[9];  const float* bv  = (const float*)d_in[10];
  const float* W11 = (const float*)d_in[11]; const float* b11 = (const float*)d_in[12];
  const float* W12 = (const float*)d_in[13]; const float* b12 = (const float*)d_in[14];
  const float* W21 = (const float*)d_in[15]; const float* b21 = (const float*)d_in[16];
  const float* W22 = (const float*)d_in[17]; const float* b22 = (const float*)d_in[18];
  float* outp = (float*)d_out;

  const long long SZ = (long long)Bv * Nv * Cv;     // 2,097,152
  // fp32 region
  float* ws    = (float*)d_ws;
  float* vpp   = ws;                       // v proj fp32 [B][N][C]
  float* rs1   = vpp + SZ;                 // MLP1 out fp32
  float* cent  = rs1 + SZ;                 // [B][K][C]
  float* cnts  = cent + Bv * Kv * Cv;      // [B][K]
  // bf16 region
  unsigned short* wt   = (unsigned short*)(cnts + Bv * Kv);
  unsigned short* qbf  = wt + 720896;      // [B][N][C] pre-scaled 0.125*log2e
  unsigned short* kbf  = qbf + SZ;
  unsigned short* vtb  = kbf + SZ;         // [B][C][N]
  unsigned short* aob  = vtb + SZ;         // attn out bf16
  unsigned short* h1b  = aob + SZ;         // MLP hidden [2N][2C]
  unsigned short* imgT = aob;              // overlay (dead after proj_k)

  // prep
  imgt_k<<<dim3(Nv / 32, Cv / 32, 6), dim3(32, 8), 0, stream>>>(q_img, k_img, v_img, imgT);
  WP wp = {{Wq, Wk, Wv, W11, W12, W21, W22}};
  wt_k<<<dim3(16, 16, 7), dim3(32, 8), 0, stream>>>(wp, wt);

  // fused q/k/v projections
  proj_k<<<dim3(32, 2, 6), 256, 0, stream>>>(imgT, wt, bq, bk, bv, qbf, kbf, vpp, vtb);

  // cluster centers
  zero_k<<<dim3(33), 256, 0, stream>>>(cent, Bv * Kv * Cv + Bv * Kv);
  center_accum<<<dim3(Bv * Kv * 8), 256, 0, stream>>>(kbf, labels, cent, cnts);
  center_norm<<<dim3(Bv * Kv * Cv / 256), 256, 0, stream>>>(cent, cnts);

  // attention: 2048 blocks (h fast -> pc rows shared across heads in LLC)
  attn_k<<<dim3(2048), 256, 0, stream>>>(qbf, kbf, vtb, cent, labels, pc, aob);

  // MLP1: h1 = leaky(aob@W11+b11); rs1 = vpp + h1@W12+b12
  mm64_k<true, 1, 0, 1><<<dim3(128, 8), 256, 0, stream>>>(
      aob, wt + 196608, b11, nullptr, nullptr, h1b, 2 * Nv, 2 * Cv, Cv);
  mm64_k<true, 0, 1, 0><<<dim3(128, 4), 256, 0, stream>>>(
      h1b, wt + 327680, b12, vpp, rs1, nullptr, 2 * Nv, Cv, 2 * Cv);

  // MLP2: h2 = leaky(rs1@W21+b21); out = rs1 + h2@W22+b22 -> [B][C][H][W]
  mm64_k<false, 1, 0, 1><<<dim3(128, 8), 256, 0, stream>>>(
      rs1, wt + 458752, b21, nullptr, nullptr, h1b, 2 * Nv, 2 * Cv, Cv);
  mm64_k<true, 0, 1, 4><<<dim3(128, 4), 256, 0, stream>>>(
      h1b, wt + 589824, b22, rs1, outp, nullptr, 2 * Nv, Cv, 2 * Cv);
}

// Round 2
// 408.300 us; speedup vs baseline: 1.5698x; 1.5698x over previous
//
#include <hip/hip_runtime.h>
#include <stdint.h>

#define Bv 2
#define Cv 256
#define Nv 4096
#define NHv 4
#define HDv 64
#define Kv 16

// R8: attn restored to R6 structure (LDS-staged K/V, 64-row q-tiles, split-m x2,
// 1024 blocks, reg-prefetch pipeline) + softmax VALU diet: exp2-domain with NO
// constant shift (shift-invariance), raw v_exp_f32, v_cvt_pk_bf16_f32 P-pack,
// register acg gather prefetched post-PV, s_setprio around MFMA clusters.
// Keeps R7's mm64 MLP grids (1024/512 blocks) and exp2-prescaled q.

typedef __attribute__((ext_vector_type(8))) short bf16x8;
typedef __attribute__((ext_vector_type(4))) float f32x4;

__device__ __forceinline__ float bf2f(unsigned short u) {
  union { unsigned int i; float f; } x; x.i = ((unsigned int)u) << 16; return x.f;
}
__device__ __forceinline__ unsigned short f2bf(float f) {
  union { float f; unsigned int i; } x; x.f = f;
  unsigned int r = x.i + 0x7FFF + ((x.i >> 16) & 1);   // RNE
  return (unsigned short)(r >> 16);
}
__device__ __forceinline__ unsigned int cvt_pk_bf16(float lo, float hi) {
  unsigned int r;
  asm("v_cvt_pk_bf16_f32 %0, %1, %2" : "=v"(r) : "v"(lo), "v"(hi));
  return r;
}
__device__ __forceinline__ float exp2_raw(float x) {
  float r;
  asm("v_exp_f32 %0, %1" : "=v"(r) : "v"(x));
  return r;
}

// ---------------------------------------------------------------------------
// Prep 1: img [b][c][n] fp32 -> imgT [z][n][c] bf16  (z = img*2 + b, z<6)
// ---------------------------------------------------------------------------
__global__ __launch_bounds__(256) void imgt_k(
    const float* __restrict__ qi, const float* __restrict__ ki,
    const float* __restrict__ vi, unsigned short* __restrict__ dst)
{
  const int z = blockIdx.z;
  const float* src = (z < 2 ? qi : (z < 4 ? ki : vi)) + (long long)(z & 1) * Cv * Nv;
  unsigned short* out = dst + (long long)z * Nv * Cv;
  __shared__ float t[32][33];
  const int x = threadIdx.x, y = threadIdx.y;
  const int n0 = blockIdx.x * 32, c0 = blockIdx.y * 32;
  for (int i = y; i < 32; i += 8)
    t[i][x] = src[(long long)(c0 + i) * Nv + n0 + x];
  __syncthreads();
  for (int i = y; i < 32; i += 8)
    out[(long long)(n0 + i) * Cv + c0 + x] = f2bf(t[x][i]);
}

// ---------------------------------------------------------------------------
// Prep 2: W [k][n] fp32 -> Wt [n][k] bf16, 7 weights packed into one buffer
// ---------------------------------------------------------------------------
struct WP { const float* p[7]; };

__global__ __launch_bounds__(256) void wt_k(WP wp, unsigned short* __restrict__ dst)
{
  const int z = blockIdx.z;
  const int KD[7] = {256, 256, 256, 256, 512, 256, 512};
  const int ND[7] = {256, 256, 256, 512, 256, 512, 256};
  const long long OFF[7] = {0, 65536, 131072, 196608, 327680, 458752, 589824};
  const int Kw = KD[z], Nw = ND[z];
  const int nb = blockIdx.x * 32, kb2 = blockIdx.y * 32;
  if (nb >= Nw || kb2 >= Kw) return;
  __shared__ float t[32][33];
  const int x = threadIdx.x, y = threadIdx.y;
  const float* src = wp.p[z];
  for (int i = y; i < 32; i += 8)
    t[i][x] = src[(long long)(kb2 + i) * Nw + nb + x];
  __syncthreads();
  for (int i = y; i < 32; i += 8)
    dst[OFF[z] + (long long)(nb + i) * Kw + kb2 + x] = f2bf(t[x][i]);
}

// ---------------------------------------------------------------------------
// Fused q/k/v projection: one dispatch, z = proj*2 + b (z<6).
// 128x128 tile, BK=64. Epilogue per proj: q->qbf(*0.125*log2e), k->kbf,
// v->vpp fp32 + vtb bf16 transposed [c][n].
// ---------------------------------------------------------------------------
__global__ __launch_bounds__(256) void proj_k(
    const unsigned short* __restrict__ imgT, const unsigned short* __restrict__ wt,
    const float* __restrict__ bq, const float* __restrict__ bk, const float* __restrict__ bv,
    unsigned short* __restrict__ qbf, unsigned short* __restrict__ kbf,
    float* __restrict__ vpp, unsigned short* __restrict__ vtb)
{
  __shared__ __align__(16) unsigned short As[128][72];
  __shared__ __align__(16) unsigned short Bs[128][72];
  const int tid = threadIdx.x;
  const int w = tid >> 6, lane = tid & 63;
  const int lr = lane & 15, quad = lane >> 4;
  const int m0 = blockIdx.x * 128, n0 = blockIdx.y * 128;
  const int z = blockIdx.z, zz = z >> 1, bb = z & 1;
  const int wm = (w >> 1) * 64, wn = (w & 1) * 64;
  const int sr = tid >> 1, sh = (tid & 1) * 32;
  const long long NvCv = (long long)Nv * Cv;

  const float* bias = zz == 0 ? bq : (zz == 1 ? bk : bv);
  const unsigned short* Ab0 = imgT + (long long)z * NvCv + (long long)(m0 + sr) * Cv + sh;
  const unsigned short* Bb0 = wt + (long long)zz * 65536 + (long long)(n0 + sr) * Cv + sh;

  f32x4 acc[4][4];
#pragma unroll
  for (int i = 0; i < 4; ++i)
#pragma unroll
    for (int j = 0; j < 4; ++j) acc[i][j] = (f32x4){0.f, 0.f, 0.f, 0.f};

  for (int k0 = 0; k0 < Cv; k0 += 64) {
    const unsigned short* Ab = Ab0 + k0;
    const unsigned short* Bp = Bb0 + k0;
    uint4 a0 = *(const uint4*)Ab, a1 = *(const uint4*)(Ab + 8);
    uint4 a2 = *(const uint4*)(Ab + 16), a3 = *(const uint4*)(Ab + 24);
    uint4 b0 = *(const uint4*)Bp, b1 = *(const uint4*)(Bp + 8);
    uint4 b2 = *(const uint4*)(Bp + 16), b3 = *(const uint4*)(Bp + 24);
    *(uint4*)&As[sr][sh] = a0; *(uint4*)&As[sr][sh + 8] = a1;
    *(uint4*)&As[sr][sh + 16] = a2; *(uint4*)&As[sr][sh + 24] = a3;
    *(uint4*)&Bs[sr][sh] = b0; *(uint4*)&Bs[sr][sh + 8] = b1;
    *(uint4*)&Bs[sr][sh + 16] = b2; *(uint4*)&Bs[sr][sh + 24] = b3;
    __syncthreads();
#pragma unroll
    for (int ks = 0; ks < 2; ++ks) {
      bf16x8 af[4], bfr[4];
#pragma unroll
      for (int i = 0; i < 4; ++i)
        af[i] = *(const bf16x8*)&As[wm + i * 16 + lr][ks * 32 + quad * 8];
#pragma unroll
      for (int j = 0; j < 4; ++j)
        bfr[j] = *(const bf16x8*)&Bs[wn + j * 16 + lr][ks * 32 + quad * 8];
#pragma unroll
      for (int i = 0; i < 4; ++i)
#pragma unroll
        for (int j = 0; j < 4; ++j)
          acc[i][j] = __builtin_amdgcn_mfma_f32_16x16x32_bf16(af[i], bfr[j], acc[i][j], 0, 0, 0);
    }
    __syncthreads();
  }

#pragma unroll
  for (int j = 0; j < 4; ++j) {
    const int col = n0 + wn + j * 16 + lr;
    const float bvv = bias[col];
#pragma unroll
    for (int i = 0; i < 4; ++i) {
      const int mb = m0 + wm + i * 16 + quad * 4;
      float r[4];
#pragma unroll
      for (int reg = 0; reg < 4; ++reg) r[reg] = acc[i][j][reg] + bvv;
      const long long ob = (long long)bb * NvCv;
      if (zz == 0) {
        // 0.125 (1/SCALE) * log2(e): softmax runs in exp2 domain
#pragma unroll
        for (int reg = 0; reg < 4; ++reg)
          qbf[ob + (long long)(mb + reg) * Cv + col] = f2bf(r[reg] * 0.18033688f);
      } else if (zz == 1) {
#pragma unroll
        for (int reg = 0; reg < 4; ++reg)
          kbf[ob + (long long)(mb + reg) * Cv + col] = f2bf(r[reg]);
      } else {
#pragma unroll
        for (int reg = 0; reg < 4; ++reg)
          vpp[ob + (long long)(mb + reg) * Cv + col] = r[reg];
        uint2 pk;
        pk.x = cvt_pk_bf16(r[0], r[1]);
        pk.y = cvt_pk_bf16(r[2], r[3]);
        *(uint2*)&vtb[ob + (long long)col * Nv + mb] = pk;
      }
    }
  }
}

// ---------------------------------------------------------------------------
// 64x64-tile bf16 MFMA GEMM for the MLPs. 4 waves in 2x2, each 32x32.
// OM: 0 fp32 [m][n]; 1 bf16 [m][n]; 4 fp32 transposed to [B][C][N].
// ---------------------------------------------------------------------------
template<bool ABF16, int ACT, int RES, int OM>
__global__ __launch_bounds__(256) void mm64_k(
    const void* __restrict__ A, const unsigned short* __restrict__ Bt,
    const float* __restrict__ bias, const float* __restrict__ Res,
    float* __restrict__ outF, unsigned short* __restrict__ outB,
    int M, int Nn, int Kd)
{
  __shared__ __align__(16) unsigned short As[64][72];
  __shared__ __align__(16) unsigned short Bs[64][72];
  const int tid = threadIdx.x;
  const int w = tid >> 6, lane = tid & 63;
  const int lr = lane & 15, quad = lane >> 4;
  const int m0 = blockIdx.x * 64, n0 = blockIdx.y * 64;
  const int wm = (w >> 1) * 32, wn = (w & 1) * 32;
  const int sr = tid >> 2, sh = (tid & 3) * 16;

  f32x4 acc[2][2];
#pragma unroll
  for (int i = 0; i < 2; ++i)
#pragma unroll
    for (int j = 0; j < 2; ++j) acc[i][j] = (f32x4){0.f, 0.f, 0.f, 0.f};

  const long long abase = (long long)(m0 + sr) * Kd + sh;
  const unsigned short* Bb = Bt + (long long)(n0 + sr) * Kd + sh;

  for (int k0 = 0; k0 < Kd; k0 += 64) {
    if (ABF16) {
      const unsigned short* Ab = (const unsigned short*)A + abase + k0;
      uint4 u0 = *(const uint4*)Ab, u1 = *(const uint4*)(Ab + 8);
      *(uint4*)&As[sr][sh] = u0; *(uint4*)&As[sr][sh + 8] = u1;
    } else {
      const float* Af = (const float*)A + abase + k0;
#pragma unroll
      for (int t = 0; t < 2; ++t) {
        const float4 f0 = *(const float4*)(Af + t * 8);
        const float4 f1 = *(const float4*)(Af + t * 8 + 4);
        uint4 pk;
        pk.x = f2bf(f0.x) | ((unsigned int)f2bf(f0.y) << 16);
        pk.y = f2bf(f0.z) | ((unsigned int)f2bf(f0.w) << 16);
        pk.z = f2bf(f1.x) | ((unsigned int)f2bf(f1.y) << 16);
        pk.w = f2bf(f1.z) | ((unsigned int)f2bf(f1.w) << 16);
        *(uint4*)&As[sr][sh + t * 8] = pk;
      }
    }
    {
      const unsigned short* Bp = Bb + k0;
      uint4 u0 = *(const uint4*)Bp, u1 = *(const uint4*)(Bp + 8);
      *(uint4*)&Bs[sr][sh] = u0; *(uint4*)&Bs[sr][sh + 8] = u1;
    }
    __syncthreads();
#pragma unroll
    for (int ks = 0; ks < 2; ++ks) {
      bf16x8 af[2], bfr[2];
#pragma unroll
      for (int i = 0; i < 2; ++i)
        af[i] = *(const bf16x8*)&As[wm + i * 16 + lr][ks * 32 + quad * 8];
#pragma unroll
      for (int j = 0; j < 2; ++j)
        bfr[j] = *(const bf16x8*)&Bs[wn + j * 16 + lr][ks * 32 + quad * 8];
#pragma unroll
      for (int i = 0; i < 2; ++i)
#pragma unroll
        for (int j = 0; j < 2; ++j)
          acc[i][j] = __builtin_amdgcn_mfma_f32_16x16x32_bf16(af[i], bfr[j], acc[i][j], 0, 0, 0);
    }
    __syncthreads();
  }

#pragma unroll
  for (int j = 0; j < 2; ++j) {
    const int col = n0 + wn + j * 16 + lr;
    const float bv = bias[col];
#pragma unroll
    for (int i = 0; i < 2; ++i) {
      const int mb = m0 + wm + i * 16 + quad * 4;
      float r[4];
#pragma unroll
      for (int reg = 0; reg < 4; ++reg) {
        float v = acc[i][j][reg] + bv;
        if (ACT) v = v > 0.f ? v : 0.01f * v;
        if (RES) v += Res[(long long)(mb + reg) * Nn + col];
        r[reg] = v;
      }
      if (OM == 0) {
#pragma unroll
        for (int reg = 0; reg < 4; ++reg)
          outF[(long long)(mb + reg) * Nn + col] = r[reg];
      } else if (OM == 1) {
#pragma unroll
        for (int reg = 0; reg < 4; ++reg)
          outB[(long long)(mb + reg) * Nn + col] = f2bf(r[reg]);
      } else {  // OM == 4: fp32 [B][C][N], m flattened over (b,n)
        const float4 st = {r[0], r[1], r[2], r[3]};
        *(float4*)&outF[((long long)((mb >> 12) * Cv + col)) * Nv + (mb & 4095)] = st;
      }
    }
  }
}

// ---------------------------------------------------------------------------
// Cluster centers
// ---------------------------------------------------------------------------
__global__ __launch_bounds__(256) void zero_k(float* p, int n)
{
  const int i = blockIdx.x * 256 + threadIdx.x;
  if (i < n) p[i] = 0.f;
}

__global__ __launch_bounds__(256) void center_accum(
    const unsigned short* __restrict__ kb, const int* __restrict__ labels,
    float* __restrict__ cent, float* __restrict__ cnts)
{
  __shared__ int lab_s[512];
  const int bx = blockIdx.x;           // Bv*Kv*8 blocks
  const int chunk = bx & 7;
  const int kk = (bx >> 3) & 15;
  const int b = bx >> 7;
  const int c = threadIdx.x;
  const int nbase = chunk * 512;
  for (int i = threadIdx.x; i < 512; i += 256) lab_s[i] = labels[b * Nv + nbase + i];
  __syncthreads();
  float acc = 0.f;
  int cnt = 0;
#pragma unroll 4
  for (int i = 0; i < 512; ++i) {
    if (lab_s[i] == kk) {              // wave-uniform branch on LDS value
      acc += bf2f(kb[(long long)(b * Nv + nbase + i) * Cv + c]);
      ++cnt;
    }
  }
  atomicAdd(&cent[(b * Kv + kk) * Cv + c], acc);
  if (c == 0) atomicAdd(&cnts[b * Kv + kk], (float)cnt);
}

__global__ __launch_bounds__(256) void center_norm(float* cent, const float* cnts)
{
  const int i = blockIdx.x * 256 + threadIdx.x;  // Bv*Kv*Cv
  cent[i] = cent[i] / (cnts[i >> 8] + 1e-6f);
}

// ---------------------------------------------------------------------------
// MFMA flash attention, split-m x2 (R6 structure), softmax VALU diet.
// Block = (part, b, h, qtile). 40,704B LDS -> 4 blocks/CU.
// p = exp2(s) with NO shift (softmax shift-invariance; q carries 0.125*log2e).
// acg gather for next tile prefetched into regs post-PV.
// Partials: opart[part][b][n][c] fp32 (un-normalized), lpart[part][b][h][n].
// ---------------------------------------------------------------------------
union PSCS {
  unsigned short p[4][16][68];   // P tiles (per wave), used in main loop
  float c[16][68];               // centers, used only in prologue
};

__global__ __launch_bounds__(256) void attn_k(
    const unsigned short* __restrict__ qb, const unsigned short* __restrict__ kb,
    const unsigned short* __restrict__ vtb, const float* __restrict__ cent,
    const int* __restrict__ labels, const float* __restrict__ pc,
    float* __restrict__ opart, float* __restrict__ lpart)
{
  __shared__ __align__(16) unsigned short q_s[64][72];
  __shared__ __align__(16) unsigned short k_s[64][72];
  __shared__ __align__(16) unsigned short vt_s[64][72];
  __shared__ __align__(16) PSCS u_s;
  __shared__ float ac_s[64][17];

  const int tid = threadIdx.x;
  const int lane = tid & 63, w = tid >> 6;
  const int lr = lane & 15, quad = lane >> 4;
  const int bx = blockIdx.x;
  const int qt = bx & 63, h = (bx >> 6) & 3, b = (bx >> 8) & 1;
  const int part = bx >> 9;
  const int n0 = qt * 64;
  const int mbase = part * 2048;
  const int sr2 = tid >> 2, so2 = (tid & 3) * 16;
  const int row_l = w * 16 + quad * 4;
  const long long pcb = (long long)b * Nv * Nv;

  // ---- prologue: stage q + centers
  {
    const unsigned short* src = qb + ((long long)(b * Nv + n0 + sr2)) * Cv + h * HDv + so2;
    *(uint4*)&q_s[sr2][so2] = *(const uint4*)src;
    *(uint4*)&q_s[sr2][so2 + 8] = *(const uint4*)(src + 8);
  }
  for (int idx = tid; idx < Kv * HDv; idx += 256)
    u_s.c[idx >> 6][idx & 63] = cent[((long long)(b * Kv + (idx >> 6))) * Cv + h * HDv + (idx & 63)];

  // issue tile-0 k/v + pc + labm loads while the block syncs
  uint4 ka0, ka1, va0, va1;
  float pc1[4][4];
  int labm1[4], labq[4];
  {
    const long long ks = ((long long)(b * Nv + mbase + sr2)) * Cv + h * HDv + so2;
    ka0 = *(const uint4*)(kb + ks); ka1 = *(const uint4*)(kb + ks + 8);
    const long long vs = ((long long)(b * Cv + h * HDv + sr2)) * Nv + mbase + so2;
    va0 = *(const uint4*)(vtb + vs); va1 = *(const uint4*)(vtb + vs + 8);
  }
#pragma unroll
  for (int sub = 0; sub < 4; ++sub) {
    labm1[sub] = labels[b * Nv + mbase + sub * 16 + lr];
#pragma unroll
    for (int reg = 0; reg < 4; ++reg)
      pc1[sub][reg] = pc[pcb + (long long)(n0 + row_l + reg) * Nv + mbase + sub * 16 + lr];
  }
#pragma unroll
  for (int reg = 0; reg < 4; ++reg) labq[reg] = labels[b * Nv + n0 + row_l + reg];

  __syncthreads();               // q_s, u_s.c visible
  // ac_s[r][k] = (q_r scaled) . center_k
  for (int idx = tid; idx < 64 * Kv; idx += 256) {
    const int r = idx >> 4, kk = idx & 15;
    float s = 0.f;
#pragma unroll
    for (int d = 0; d < HDv; ++d) s += bf2f(q_s[r][d]) * u_s.c[kk][d];
    ac_s[r][kk] = s;
  }
  const bf16x8 qa0 = *(const bf16x8*)&q_s[w * 16 + lr][quad * 8];
  const bf16x8 qa1 = *(const bf16x8*)&q_s[w * 16 + lr][32 + quad * 8];
  __syncthreads();               // ac_s visible; all waves done with u_s.c

  // tile-0 acg gather (register-resident select operand)
  float acg[4][4];
#pragma unroll
  for (int sub = 0; sub < 4; ++sub)
#pragma unroll
    for (int reg = 0; reg < 4; ++reg)
      acg[sub][reg] = ac_s[row_l + reg][labm1[sub]];

  // stage tile 0 from regs
  *(uint4*)&k_s[sr2][so2] = ka0; *(uint4*)&k_s[sr2][so2 + 8] = ka1;
  *(uint4*)&vt_s[sr2][so2] = va0; *(uint4*)&vt_s[sr2][so2 + 8] = va1;
  __syncthreads();               // tile 0 visible

  f32x4 oacc[4];
#pragma unroll
  for (int s2 = 0; s2 < 4; ++s2) oacc[s2] = (f32x4){0.f, 0.f, 0.f, 0.f};
  float lrow[4] = {0.f, 0.f, 0.f, 0.f};

  for (int t = 0; t < 32; ++t) {
    const int m0 = mbase + t * 64;
    const bool has = (t < 31);

    // prefetch next tile k/v into regs (hidden behind this tile's compute)
    if (has) {
      const long long ks = ((long long)(b * Nv + m0 + 64 + sr2)) * Cv + h * HDv + so2;
      ka0 = *(const uint4*)(kb + ks); ka1 = *(const uint4*)(kb + ks + 8);
      const long long vs = ((long long)(b * Cv + h * HDv + sr2)) * Nv + m0 + 64 + so2;
      va0 = *(const uint4*)(vtb + vs); va1 = *(const uint4*)(vtb + vs + 8);
    }

    // QK^T
    f32x4 sacc[4];
    __builtin_amdgcn_s_setprio(1);
#pragma unroll
    for (int sub = 0; sub < 4; ++sub) {
      const bf16x8 kb0 = *(const bf16x8*)&k_s[sub * 16 + lr][quad * 8];
      const bf16x8 kb1 = *(const bf16x8*)&k_s[sub * 16 + lr][32 + quad * 8];
      f32x4 s = (f32x4){0.f, 0.f, 0.f, 0.f};
      s = __builtin_amdgcn_mfma_f32_16x16x32_bf16(qa0, kb0, s, 0, 0, 0);
      s = __builtin_amdgcn_mfma_f32_16x16x32_bf16(qa1, kb1, s, 0, 0, 0);
      sacc[sub] = s;
    }
    __builtin_amdgcn_s_setprio(0);

    // adaptive select + exp2(s), cvt_pk P pack, accumulate denominator
#pragma unroll
    for (int sub = 0; sub < 4; ++sub) {
      float p4[4];
#pragma unroll
      for (int reg = 0; reg < 4; ++reg) {
        const float s = (labm1[sub] == labq[reg]) ? sacc[sub][reg]
                                                  : acg[sub][reg] * pc1[sub][reg];
        const float p = exp2_raw(s);
        lrow[reg] += p;
        p4[reg] = p;
      }
      const unsigned int pk01 = cvt_pk_bf16(p4[0], p4[1]);
      const unsigned int pk23 = cvt_pk_bf16(p4[2], p4[3]);
      unsigned short* pp = &u_s.p[w][quad * 4][sub * 16 + lr];
      pp[0]   = (unsigned short)pk01;
      pp[68]  = (unsigned short)(pk01 >> 16);
      pp[136] = (unsigned short)pk23;
      pp[204] = (unsigned short)(pk23 >> 16);
    }

    // pc/labm consumed -> issue next tile's loads (covers PV + barriers + QK)
    if (has) {
#pragma unroll
      for (int sub = 0; sub < 4; ++sub) {
        labm1[sub] = labels[b * Nv + m0 + 64 + sub * 16 + lr];
#pragma unroll
        for (int reg = 0; reg < 4; ++reg)
          pc1[sub][reg] = pc[pcb + (long long)(n0 + row_l + reg) * Nv + m0 + 64 + sub * 16 + lr];
      }
    }

    // PV (same-wave LDS in-order)
    const bf16x8 pa0 = *(const bf16x8*)&u_s.p[w][lr][quad * 8];
    const bf16x8 pa1 = *(const bf16x8*)&u_s.p[w][lr][32 + quad * 8];
    __builtin_amdgcn_s_setprio(1);
#pragma unroll
    for (int sub = 0; sub < 4; ++sub) {
      const bf16x8 vb0 = *(const bf16x8*)&vt_s[sub * 16 + lr][quad * 8];
      const bf16x8 vb1 = *(const bf16x8*)&vt_s[sub * 16 + lr][32 + quad * 8];
      oacc[sub] = __builtin_amdgcn_mfma_f32_16x16x32_bf16(pa0, vb0, oacc[sub], 0, 0, 0);
      oacc[sub] = __builtin_amdgcn_mfma_f32_16x16x32_bf16(pa1, vb1, oacc[sub], 0, 0, 0);
    }
    __builtin_amdgcn_s_setprio(0);

    // gather next tile's acg (labm1 already in flight; LDS latency hides
    // under the barrier + staging + next QK)
    if (has) {
#pragma unroll
      for (int sub = 0; sub < 4; ++sub)
#pragma unroll
        for (int reg = 0; reg < 4; ++reg)
          acg[sub][reg] = ac_s[row_l + reg][labm1[sub]];
    }

    __syncthreads();             // all waves done reading k_s/vt_s
    if (has) {
      *(uint4*)&k_s[sr2][so2] = ka0; *(uint4*)&k_s[sr2][so2 + 8] = ka1;
      *(uint4*)&vt_s[sr2][so2] = va0; *(uint4*)&vt_s[sr2][so2 + 8] = va1;
    }
    __syncthreads();             // next tile visible
  }

  // epilogue: partial sums (no normalization; combine_k divides)
#pragma unroll
  for (int reg = 0; reg < 4; ++reg) {
    float l = lrow[reg];
    l += __shfl_xor(l, 1); l += __shfl_xor(l, 2);
    l += __shfl_xor(l, 4); l += __shfl_xor(l, 8);
    const int row = n0 + row_l + reg;
    const long long obase = (long long)part * 2097152 + ((long long)(b * Nv + row)) * Cv + h * HDv;
#pragma unroll
    for (int sub = 0; sub < 4; ++sub)
      opart[obase + sub * 16 + lr] = oacc[sub][reg];
    if (lr == 0)
      lpart[part * 32768 + (b * 4 + h) * 4096 + row] = l;
  }
}

// ---------------------------------------------------------------------------
// Combine split-m partials: aob = (o0+o1)/(l0+l1), bf16
// ---------------------------------------------------------------------------
__global__ __launch_bounds__(256) void combine_k(
    const float* __restrict__ op, const float* __restrict__ lp,
    unsigned short* __restrict__ aob)
{
  const long long i4 = ((long long)blockIdx.x * 256 + threadIdx.x) * 4;
  const int c = (int)(i4 & 255), n = (int)((i4 >> 8) & 4095), b = (int)(i4 >> 20);
  const int h = c >> 6;
  const float l = lp[(b * 4 + h) * 4096 + n] + lp[32768 + (b * 4 + h) * 4096 + n];
  const float inv = 1.f / l;
  const float4 a = *(const float4*)&op[i4];
  const float4 d = *(const float4*)&op[2097152 + i4];
  uint2 pk;
  pk.x = cvt_pk_bf16((a.x + d.x) * inv, (a.y + d.y) * inv);
  pk.y = cvt_pk_bf16((a.z + d.z) * inv, (a.w + d.w) * inv);
  *(uint2*)&aob[i4] = pk;
}

// ---------------------------------------------------------------------------
extern "C" void kernel_launch(void* const* d_in, const int* in_sizes, int n_in,
                              void* d_out, int out_size, void* d_ws, size_t ws_size,
                              hipStream_t stream)
{
  const float* q_img = (const float*)d_in[0];
  const float* k_img = (const float*)d_in[1];
  const float* v_img = (const float*)d_in[2];
  const int* labels  = (const int*)d_in[3];
  const float* pc    = (const float*)d_in[4];
  const float* Wq  = (const float*)d_in[5];  const float* bq  = (const float*)d_in[6];
  const float* Wk  = (const float*)d_in[7];  const float* bk  = (const float*)d_in[8];
  const float* Wv  = (const float*)d_in[9];  const float* bv  = (const float*)d_in[10];
  const float* W11 = (const float*)d_in[11]; const float* b11 = (const float*)d_in[12];
  const float* W12 = (const float*)d_in[13]; const float* b12 = (const float*)d_in[14];
  const float* W21 = (const float*)d_in[15]; const float* b21 = (const float*)d_in[16];
  const float* W22 = (const float*)d_in[17]; const float* b22 = (const float*)d_in[18];
  float* outp = (float*)d_out;

  const long long SZ = (long long)Bv * Nv * Cv;     // 2,097,152
  // fp32 region (~32.3 MB)
  float* ws    = (float*)d_ws;
  float* vpp   = ws;                       // v proj fp32
  float* rs1   = vpp + SZ;                 // MLP1 out fp32
  float* opart = rs1 + SZ;                 // attn partials [2][B][N][C]
  float* lpart = opart + 2 * SZ;           // [2][B][NH][N]
  float* cent  = lpart + 65536;            // [B][K][C]
  float* cnts  = cent + Bv * Kv * Cv;      // [B][K]
  // bf16 region (~25.4 MB)
  unsigned short* wt   = (unsigned short*)(cnts + Bv * Kv);
  unsigned short* qbf  = wt + 720896;      // [B][N][C] pre-scaled 0.125*log2e
  unsigned short* kbf  = qbf + SZ;
  unsigned short* vtb  = kbf + SZ;         // [B][C][N]
  unsigned short* aob  = vtb + SZ;         // attn out bf16
  unsigned short* h1b  = aob + SZ;         // MLP hidden [2N][2C]
  unsigned short* imgT = aob;              // overlay (dead after proj_k)

  // prep
  imgt_k<<<dim3(Nv / 32, Cv / 32, 6), dim3(32, 8), 0, stream>>>(q_img, k_img, v_img, imgT);
  WP wp = {{Wq, Wk, Wv, W11, W12, W21, W22}};
  wt_k<<<dim3(16, 16, 7), dim3(32, 8), 0, stream>>>(wp, wt);

  // fused q/k/v projections (one dispatch, 384 blocks)
  proj_k<<<dim3(32, 2, 6), 256, 0, stream>>>(imgT, wt, bq, bk, bv, qbf, kbf, vpp, vtb);

  // cluster centers
  zero_k<<<dim3(33), 256, 0, stream>>>(cent, Bv * Kv * Cv + Bv * Kv);
  center_accum<<<dim3(Bv * Kv * 8), 256, 0, stream>>>(kbf, labels, cent, cnts);
  center_norm<<<dim3(Bv * Kv * Cv / 256), 256, 0, stream>>>(cent, cnts);

  // attention (split-m x2) + combine
  attn_k<<<dim3(1024), 256, 0, stream>>>(qbf, kbf, vtb, cent, labels, pc, opart, lpart);
  combine_k<<<dim3(2048), 256, 0, stream>>>(opart, lpart, aob);

  // MLP1: h1 = leaky(aob@W11+b11); rs1 = vpp + h1@W12+b12
  mm64_k<true, 1, 0, 1><<<dim3(128, 8), 256, 0, stream>>>(
      aob, wt + 196608, b11, nullptr, nullptr, h1b, 2 * Nv, 2 * Cv, Cv);
  mm64_k<true, 0, 1, 0><<<dim3(128, 4), 256, 0, stream>>>(
      h1b, wt + 327680, b12, vpp, rs1, nullptr, 2 * Nv, Cv, 2 * Cv);

  // MLP2: h2 = leaky(rs1@W21+b21); out = rs1 + h2@W22+b22 -> [B][C][H][W]
  mm64_k<false, 1, 0, 1><<<dim3(128, 8), 256, 0, stream>>>(
      rs1, wt + 458752, b21, nullptr, nullptr, h1b, 2 * Nv, 2 * Cv, Cv);
  mm64_k<true, 0, 1, 4><<<dim3(128, 4), 256, 0, stream>>>(
      h1b, wt + 589824, b22, rs1, outp, nullptr, 2 * Nv, Cv, 2 * Cv);
}

// Round 3
// 406.973 us; speedup vs baseline: 1.5749x; 1.0033x over previous
//
#include <hip/hip_runtime.h>
#include <stdint.h>

#define Bv 2
#define Cv 256
#define Nv 4096
#define NHv 4
#define HDv 64
#define Kv 16

// R9: attn addressing diet (running pc/label pointers w/ immediate offsets,
// wave-uniform k/v bases -> SALU bumps). proj_k -> 64x64 tiles (1536 blocks,
// 6/CU vs 1.5/CU). All GEMM K-loops get register prefetch pipeline (issue
// next K-tile's global loads during current tile's MFMA).

typedef __attribute__((ext_vector_type(8))) short bf16x8;
typedef __attribute__((ext_vector_type(4))) float f32x4;

__device__ __forceinline__ float bf2f(unsigned short u) {
  union { unsigned int i; float f; } x; x.i = ((unsigned int)u) << 16; return x.f;
}
__device__ __forceinline__ unsigned short f2bf(float f) {
  union { float f; unsigned int i; } x; x.f = f;
  unsigned int r = x.i + 0x7FFF + ((x.i >> 16) & 1);   // RNE
  return (unsigned short)(r >> 16);
}
__device__ __forceinline__ unsigned int cvt_pk_bf16(float lo, float hi) {
  unsigned int r;
  asm("v_cvt_pk_bf16_f32 %0, %1, %2" : "=v"(r) : "v"(lo), "v"(hi));
  return r;
}
__device__ __forceinline__ float exp2_raw(float x) {
  float r;
  asm("v_exp_f32 %0, %1" : "=v"(r) : "v"(x));
  return r;
}

// ---------------------------------------------------------------------------
// Prep 1: img [b][c][n] fp32 -> imgT [z][n][c] bf16  (z = img*2 + b, z<6)
// ---------------------------------------------------------------------------
__global__ __launch_bounds__(256) void imgt_k(
    const float* __restrict__ qi, const float* __restrict__ ki,
    const float* __restrict__ vi, unsigned short* __restrict__ dst)
{
  const int z = blockIdx.z;
  const float* src = (z < 2 ? qi : (z < 4 ? ki : vi)) + (long long)(z & 1) * Cv * Nv;
  unsigned short* out = dst + (long long)z * Nv * Cv;
  __shared__ float t[32][33];
  const int x = threadIdx.x, y = threadIdx.y;
  const int n0 = blockIdx.x * 32, c0 = blockIdx.y * 32;
  for (int i = y; i < 32; i += 8)
    t[i][x] = src[(long long)(c0 + i) * Nv + n0 + x];
  __syncthreads();
  for (int i = y; i < 32; i += 8)
    out[(long long)(n0 + i) * Cv + c0 + x] = f2bf(t[x][i]);
}

// ---------------------------------------------------------------------------
// Prep 2: W [k][n] fp32 -> Wt [n][k] bf16, 7 weights packed into one buffer
// ---------------------------------------------------------------------------
struct WP { const float* p[7]; };

__global__ __launch_bounds__(256) void wt_k(WP wp, unsigned short* __restrict__ dst)
{
  const int z = blockIdx.z;
  const int KD[7] = {256, 256, 256, 256, 512, 256, 512};
  const int ND[7] = {256, 256, 256, 512, 256, 512, 256};
  const long long OFF[7] = {0, 65536, 131072, 196608, 327680, 458752, 589824};
  const int Kw = KD[z], Nw = ND[z];
  const int nb = blockIdx.x * 32, kb2 = blockIdx.y * 32;
  if (nb >= Nw || kb2 >= Kw) return;
  __shared__ float t[32][33];
  const int x = threadIdx.x, y = threadIdx.y;
  const float* src = wp.p[z];
  for (int i = y; i < 32; i += 8)
    t[i][x] = src[(long long)(kb2 + i) * Nw + nb + x];
  __syncthreads();
  for (int i = y; i < 32; i += 8)
    dst[OFF[z] + (long long)(nb + i) * Kw + kb2 + x] = f2bf(t[x][i]);
}

// ---------------------------------------------------------------------------
// Fused q/k/v projection, 64x64 tiles (z = proj*2 + b, z<6). 1536 blocks.
// Register-prefetch K pipeline. Epilogue per proj: q->qbf(*0.125*log2e),
// k->kbf, v->vpp fp32 + vtb bf16 transposed [c][n].
// ---------------------------------------------------------------------------
__global__ __launch_bounds__(256) void proj64_k(
    const unsigned short* __restrict__ imgT, const unsigned short* __restrict__ wt,
    const float* __restrict__ bq, const float* __restrict__ bk, const float* __restrict__ bv,
    unsigned short* __restrict__ qbf, unsigned short* __restrict__ kbf,
    float* __restrict__ vpp, unsigned short* __restrict__ vtb)
{
  __shared__ __align__(16) unsigned short As[64][72];
  __shared__ __align__(16) unsigned short Bs[64][72];
  const int tid = threadIdx.x;
  const int w = tid >> 6, lane = tid & 63;
  const int lr = lane & 15, quad = lane >> 4;
  const int m0 = blockIdx.x * 64, n0 = blockIdx.y * 64;
  const int z = blockIdx.z, zz = z >> 1, bb = z & 1;
  const int wm = (w >> 1) * 32, wn = (w & 1) * 32;
  const int sr = tid >> 2, sh = (tid & 3) * 16;
  const long long NvCv = (long long)Nv * Cv;

  const float* bias = zz == 0 ? bq : (zz == 1 ? bk : bv);
  const unsigned short* Ab0 = imgT + (long long)z * NvCv + (long long)(m0 + sr) * Cv + sh;
  const unsigned short* Bb0 = wt + (long long)zz * 65536 + (long long)(n0 + sr) * Cv + sh;

  f32x4 acc[2][2];
#pragma unroll
  for (int i = 0; i < 2; ++i)
#pragma unroll
    for (int j = 0; j < 2; ++j) acc[i][j] = (f32x4){0.f, 0.f, 0.f, 0.f};

  uint4 rA0 = *(const uint4*)Ab0, rA1 = *(const uint4*)(Ab0 + 8);
  uint4 rB0 = *(const uint4*)Bb0, rB1 = *(const uint4*)(Bb0 + 8);

  for (int k0 = 0; k0 < Cv; k0 += 64) {
    *(uint4*)&As[sr][sh] = rA0; *(uint4*)&As[sr][sh + 8] = rA1;
    *(uint4*)&Bs[sr][sh] = rB0; *(uint4*)&Bs[sr][sh + 8] = rB1;
    __syncthreads();
    if (k0 + 64 < Cv) {
      rA0 = *(const uint4*)(Ab0 + k0 + 64); rA1 = *(const uint4*)(Ab0 + k0 + 72);
      rB0 = *(const uint4*)(Bb0 + k0 + 64); rB1 = *(const uint4*)(Bb0 + k0 + 72);
    }
#pragma unroll
    for (int ks = 0; ks < 2; ++ks) {
      bf16x8 af[2], bfr[2];
#pragma unroll
      for (int i = 0; i < 2; ++i)
        af[i] = *(const bf16x8*)&As[wm + i * 16 + lr][ks * 32 + quad * 8];
#pragma unroll
      for (int j = 0; j < 2; ++j)
        bfr[j] = *(const bf16x8*)&Bs[wn + j * 16 + lr][ks * 32 + quad * 8];
#pragma unroll
      for (int i = 0; i < 2; ++i)
#pragma unroll
        for (int j = 0; j < 2; ++j)
          acc[i][j] = __builtin_amdgcn_mfma_f32_16x16x32_bf16(af[i], bfr[j], acc[i][j], 0, 0, 0);
    }
    __syncthreads();
  }

#pragma unroll
  for (int j = 0; j < 2; ++j) {
    const int col = n0 + wn + j * 16 + lr;
    const float bvv = bias[col];
#pragma unroll
    for (int i = 0; i < 2; ++i) {
      const int mb = m0 + wm + i * 16 + quad * 4;
      float r[4];
#pragma unroll
      for (int reg = 0; reg < 4; ++reg) r[reg] = acc[i][j][reg] + bvv;
      const long long ob = (long long)bb * NvCv;
      if (zz == 0) {
        // 0.125 (1/SCALE) * log2(e): softmax runs in exp2 domain
#pragma unroll
        for (int reg = 0; reg < 4; ++reg)
          qbf[ob + (long long)(mb + reg) * Cv + col] = f2bf(r[reg] * 0.18033688f);
      } else if (zz == 1) {
#pragma unroll
        for (int reg = 0; reg < 4; ++reg)
          kbf[ob + (long long)(mb + reg) * Cv + col] = f2bf(r[reg]);
      } else {
#pragma unroll
        for (int reg = 0; reg < 4; ++reg)
          vpp[ob + (long long)(mb + reg) * Cv + col] = r[reg];
        uint2 pk;
        pk.x = cvt_pk_bf16(r[0], r[1]);
        pk.y = cvt_pk_bf16(r[2], r[3]);
        *(uint2*)&vtb[ob + (long long)col * Nv + mb] = pk;
      }
    }
  }
}

// ---------------------------------------------------------------------------
// 64x64-tile bf16 MFMA GEMM for the MLPs, register-prefetch K pipeline.
// OM: 0 fp32 [m][n]; 1 bf16 [m][n]; 4 fp32 transposed to [B][C][N].
// ---------------------------------------------------------------------------
template<bool ABF16, int ACT, int RES, int OM>
__global__ __launch_bounds__(256) void mm64_k(
    const void* __restrict__ A, const unsigned short* __restrict__ Bt,
    const float* __restrict__ bias, const float* __restrict__ Res,
    float* __restrict__ outF, unsigned short* __restrict__ outB,
    int M, int Nn, int Kd)
{
  __shared__ __align__(16) unsigned short As[64][72];
  __shared__ __align__(16) unsigned short Bs[64][72];
  const int tid = threadIdx.x;
  const int w = tid >> 6, lane = tid & 63;
  const int lr = lane & 15, quad = lane >> 4;
  const int m0 = blockIdx.x * 64, n0 = blockIdx.y * 64;
  const int wm = (w >> 1) * 32, wn = (w & 1) * 32;
  const int sr = tid >> 2, sh = (tid & 3) * 16;

  f32x4 acc[2][2];
#pragma unroll
  for (int i = 0; i < 2; ++i)
#pragma unroll
    for (int j = 0; j < 2; ++j) acc[i][j] = (f32x4){0.f, 0.f, 0.f, 0.f};

  const long long abase = (long long)(m0 + sr) * Kd + sh;
  const unsigned short* Bb = Bt + (long long)(n0 + sr) * Kd + sh;

  uint4 rA0, rA1, rB0, rB1;
  float4 fA[4];
  if (ABF16) {
    const unsigned short* Ab = (const unsigned short*)A + abase;
    rA0 = *(const uint4*)Ab; rA1 = *(const uint4*)(Ab + 8);
  } else {
    const float* Af = (const float*)A + abase;
    fA[0] = *(const float4*)Af;      fA[1] = *(const float4*)(Af + 4);
    fA[2] = *(const float4*)(Af + 8); fA[3] = *(const float4*)(Af + 12);
  }
  rB0 = *(const uint4*)Bb; rB1 = *(const uint4*)(Bb + 8);

  for (int k0 = 0; k0 < Kd; k0 += 64) {
    if (ABF16) {
      *(uint4*)&As[sr][sh] = rA0; *(uint4*)&As[sr][sh + 8] = rA1;
    } else {
#pragma unroll
      for (int t = 0; t < 2; ++t) {
        uint4 pk;
        pk.x = cvt_pk_bf16(fA[t * 2].x, fA[t * 2].y);
        pk.y = cvt_pk_bf16(fA[t * 2].z, fA[t * 2].w);
        pk.z = cvt_pk_bf16(fA[t * 2 + 1].x, fA[t * 2 + 1].y);
        pk.w = cvt_pk_bf16(fA[t * 2 + 1].z, fA[t * 2 + 1].w);
        *(uint4*)&As[sr][sh + t * 8] = pk;
      }
    }
    *(uint4*)&Bs[sr][sh] = rB0; *(uint4*)&Bs[sr][sh + 8] = rB1;
    __syncthreads();
    if (k0 + 64 < Kd) {
      if (ABF16) {
        const unsigned short* Ab = (const unsigned short*)A + abase + k0 + 64;
        rA0 = *(const uint4*)Ab; rA1 = *(const uint4*)(Ab + 8);
      } else {
        const float* Af = (const float*)A + abase + k0 + 64;
        fA[0] = *(const float4*)Af;      fA[1] = *(const float4*)(Af + 4);
        fA[2] = *(const float4*)(Af + 8); fA[3] = *(const float4*)(Af + 12);
      }
      rB0 = *(const uint4*)(Bb + k0 + 64); rB1 = *(const uint4*)(Bb + k0 + 72);
    }
#pragma unroll
    for (int ks = 0; ks < 2; ++ks) {
      bf16x8 af[2], bfr[2];
#pragma unroll
      for (int i = 0; i < 2; ++i)
        af[i] = *(const bf16x8*)&As[wm + i * 16 + lr][ks * 32 + quad * 8];
#pragma unroll
      for (int j = 0; j < 2; ++j)
        bfr[j] = *(const bf16x8*)&Bs[wn + j * 16 + lr][ks * 32 + quad * 8];
#pragma unroll
      for (int i = 0; i < 2; ++i)
#pragma unroll
        for (int j = 0; j < 2; ++j)
          acc[i][j] = __builtin_amdgcn_mfma_f32_16x16x32_bf16(af[i], bfr[j], acc[i][j], 0, 0, 0);
    }
    __syncthreads();
  }

#pragma unroll
  for (int j = 0; j < 2; ++j) {
    const int col = n0 + wn + j * 16 + lr;
    const float bv = bias[col];
#pragma unroll
    for (int i = 0; i < 2; ++i) {
      const int mb = m0 + wm + i * 16 + quad * 4;
      float r[4];
#pragma unroll
      for (int reg = 0; reg < 4; ++reg) {
        float v = acc[i][j][reg] + bv;
        if (ACT) v = v > 0.f ? v : 0.01f * v;
        if (RES) v += Res[(long long)(mb + reg) * Nn + col];
        r[reg] = v;
      }
      if (OM == 0) {
#pragma unroll
        for (int reg = 0; reg < 4; ++reg)
          outF[(long long)(mb + reg) * Nn + col] = r[reg];
      } else if (OM == 1) {
#pragma unroll
        for (int reg = 0; reg < 4; ++reg)
          outB[(long long)(mb + reg) * Nn + col] = f2bf(r[reg]);
      } else {  // OM == 4: fp32 [B][C][N], m flattened over (b,n)
        const float4 st = {r[0], r[1], r[2], r[3]};
        *(float4*)&outF[((long long)((mb >> 12) * Cv + col)) * Nv + (mb & 4095)] = st;
      }
    }
  }
}

// ---------------------------------------------------------------------------
// Cluster centers
// ---------------------------------------------------------------------------
__global__ __launch_bounds__(256) void zero_k(float* p, int n)
{
  const int i = blockIdx.x * 256 + threadIdx.x;
  if (i < n) p[i] = 0.f;
}

__global__ __launch_bounds__(256) void center_accum(
    const unsigned short* __restrict__ kb, const int* __restrict__ labels,
    float* __restrict__ cent, float* __restrict__ cnts)
{
  __shared__ int lab_s[512];
  const int bx = blockIdx.x;           // Bv*Kv*8 blocks
  const int chunk = bx & 7;
  const int kk = (bx >> 3) & 15;
  const int b = bx >> 7;
  const int c = threadIdx.x;
  const int nbase = chunk * 512;
  for (int i = threadIdx.x; i < 512; i += 256) lab_s[i] = labels[b * Nv + nbase + i];
  __syncthreads();
  float acc = 0.f;
  int cnt = 0;
#pragma unroll 4
  for (int i = 0; i < 512; ++i) {
    if (lab_s[i] == kk) {              // wave-uniform branch on LDS value
      acc += bf2f(kb[(long long)(b * Nv + nbase + i) * Cv + c]);
      ++cnt;
    }
  }
  atomicAdd(&cent[(b * Kv + kk) * Cv + c], acc);
  if (c == 0) atomicAdd(&cnts[b * Kv + kk], (float)cnt);
}

__global__ __launch_bounds__(256) void center_norm(float* cent, const float* cnts)
{
  const int i = blockIdx.x * 256 + threadIdx.x;  // Bv*Kv*Cv
  cent[i] = cent[i] / (cnts[i >> 8] + 1e-6f);
}

// ---------------------------------------------------------------------------
// MFMA flash attention, split-m x2, addressing diet.
// Running pointers: pc/labels bumped +64/tile (loads use immediate offsets);
// k/v via wave-uniform base (SGPR) + lane-const 32-bit offset.
// p = exp2(s), no shift (q carries 0.125*log2e). cvt_pk P pack.
// Partials: opart[part][b][n][c] fp32, lpart[part][b][h][n].
// ---------------------------------------------------------------------------
union PSCS {
  unsigned short p[4][16][68];   // P tiles (per wave), used in main loop
  float c[16][68];               // centers, used only in prologue
};

__global__ __launch_bounds__(256) void attn_k(
    const unsigned short* __restrict__ qb, const unsigned short* __restrict__ kb,
    const unsigned short* __restrict__ vtb, const float* __restrict__ cent,
    const int* __restrict__ labels, const float* __restrict__ pc,
    float* __restrict__ opart, float* __restrict__ lpart)
{
  __shared__ __align__(16) unsigned short q_s[64][72];
  __shared__ __align__(16) unsigned short k_s[64][72];
  __shared__ __align__(16) unsigned short vt_s[64][72];
  __shared__ __align__(16) PSCS u_s;
  __shared__ float ac_s[64][17];

  const int tid = threadIdx.x;
  const int lane = tid & 63, w = tid >> 6;
  const int lr = lane & 15, quad = lane >> 4;
  const int bx = blockIdx.x;
  const int qt = bx & 63, h = (bx >> 6) & 3, b = (bx >> 8) & 1;
  const int part = bx >> 9;
  const int n0 = qt * 64;
  const int mbase = part * 2048;
  const int sr2 = tid >> 2, so2 = (tid & 3) * 16;
  const int row_l = w * 16 + quad * 4;
  const long long pcb = (long long)b * Nv * Nv;

  // ---- prologue: stage q + centers
  {
    const unsigned short* src = qb + ((long long)(b * Nv + n0 + sr2)) * Cv + h * HDv + so2;
    *(uint4*)&q_s[sr2][so2] = *(const uint4*)src;
    *(uint4*)&q_s[sr2][so2 + 8] = *(const uint4*)(src + 8);
  }
  for (int idx = tid; idx < Kv * HDv; idx += 256)
    u_s.c[idx >> 6][idx & 63] = cent[((long long)(b * Kv + (idx >> 6))) * Cv + h * HDv + (idx & 63)];

  // running pointers (uniform bases advance by SALU; lane parts are constant)
  const unsigned short* kub = kb + ((long long)(b * Nv + mbase)) * Cv + h * HDv;
  const unsigned short* vub = vtb + ((long long)(b * Cv + h * HDv)) * Nv + mbase;
  const int koff = sr2 * Cv + so2;
  const int voff = sr2 * Nv + so2;
  const int* lbp = labels + b * Nv + mbase + lr;
  const float* pcp[4];
#pragma unroll
  for (int reg = 0; reg < 4; ++reg)
    pcp[reg] = pc + pcb + (long long)(n0 + row_l + reg) * Nv + mbase + lr;

  // issue tile-0 k/v + pc + labm loads while the block syncs
  uint4 ka0, ka1, va0, va1;
  float pc1[4][4];
  int labm1[4], labq[4];
  ka0 = *(const uint4*)(kub + koff); ka1 = *(const uint4*)(kub + koff + 8);
  va0 = *(const uint4*)(vub + voff); va1 = *(const uint4*)(vub + voff + 8);
  kub += 64 * Cv; vub += 64;
#pragma unroll
  for (int sub = 0; sub < 4; ++sub) {
    labm1[sub] = lbp[sub * 16];
#pragma unroll
    for (int reg = 0; reg < 4; ++reg)
      pc1[sub][reg] = pcp[reg][sub * 16];
  }
  lbp += 64;
#pragma unroll
  for (int reg = 0; reg < 4; ++reg) pcp[reg] += 64;
#pragma unroll
  for (int reg = 0; reg < 4; ++reg) labq[reg] = labels[b * Nv + n0 + row_l + reg];

  __syncthreads();               // q_s, u_s.c visible
  // ac_s[r][k] = (q_r scaled) . center_k
  for (int idx = tid; idx < 64 * Kv; idx += 256) {
    const int r = idx >> 4, kk = idx & 15;
    float s = 0.f;
#pragma unroll
    for (int d = 0; d < HDv; ++d) s += bf2f(q_s[r][d]) * u_s.c[kk][d];
    ac_s[r][kk] = s;
  }
  const bf16x8 qa0 = *(const bf16x8*)&q_s[w * 16 + lr][quad * 8];
  const bf16x8 qa1 = *(const bf16x8*)&q_s[w * 16 + lr][32 + quad * 8];
  __syncthreads();               // ac_s visible; all waves done with u_s.c

  // tile-0 acg gather (register-resident select operand)
  float acg[4][4];
#pragma unroll
  for (int sub = 0; sub < 4; ++sub)
#pragma unroll
    for (int reg = 0; reg < 4; ++reg)
      acg[sub][reg] = ac_s[row_l + reg][labm1[sub]];

  // stage tile 0 from regs
  *(uint4*)&k_s[sr2][so2] = ka0; *(uint4*)&k_s[sr2][so2 + 8] = ka1;
  *(uint4*)&vt_s[sr2][so2] = va0; *(uint4*)&vt_s[sr2][so2 + 8] = va1;
  __syncthreads();               // tile 0 visible

  f32x4 oacc[4];
#pragma unroll
  for (int s2 = 0; s2 < 4; ++s2) oacc[s2] = (f32x4){0.f, 0.f, 0.f, 0.f};
  float lrow[4] = {0.f, 0.f, 0.f, 0.f};

  for (int t = 0; t < 32; ++t) {
    const bool has = (t < 31);

    // prefetch next tile k/v into regs (hidden behind this tile's compute)
    if (has) {
      ka0 = *(const uint4*)(kub + koff); ka1 = *(const uint4*)(kub + koff + 8);
      va0 = *(const uint4*)(vub + voff); va1 = *(const uint4*)(vub + voff + 8);
      kub += 64 * Cv; vub += 64;
    }

    // QK^T
    f32x4 sacc[4];
    __builtin_amdgcn_s_setprio(1);
#pragma unroll
    for (int sub = 0; sub < 4; ++sub) {
      const bf16x8 kb0 = *(const bf16x8*)&k_s[sub * 16 + lr][quad * 8];
      const bf16x8 kb1 = *(const bf16x8*)&k_s[sub * 16 + lr][32 + quad * 8];
      f32x4 s = (f32x4){0.f, 0.f, 0.f, 0.f};
      s = __builtin_amdgcn_mfma_f32_16x16x32_bf16(qa0, kb0, s, 0, 0, 0);
      s = __builtin_amdgcn_mfma_f32_16x16x32_bf16(qa1, kb1, s, 0, 0, 0);
      sacc[sub] = s;
    }
    __builtin_amdgcn_s_setprio(0);

    // adaptive select + exp2(s), cvt_pk P pack, accumulate denominator
#pragma unroll
    for (int sub = 0; sub < 4; ++sub) {
      float p4[4];
#pragma unroll
      for (int reg = 0; reg < 4; ++reg) {
        const float s = (labm1[sub] == labq[reg]) ? sacc[sub][reg]
                                                  : acg[sub][reg] * pc1[sub][reg];
        const float p = exp2_raw(s);
        lrow[reg] += p;
        p4[reg] = p;
      }
      const unsigned int pk01 = cvt_pk_bf16(p4[0], p4[1]);
      const unsigned int pk23 = cvt_pk_bf16(p4[2], p4[3]);
      unsigned short* pp = &u_s.p[w][quad * 4][sub * 16 + lr];
      pp[0]   = (unsigned short)pk01;
      pp[68]  = (unsigned short)(pk01 >> 16);
      pp[136] = (unsigned short)pk23;
      pp[204] = (unsigned short)(pk23 >> 16);
    }

    // pc/labm consumed -> issue next tile's loads (covers PV + barriers + QK)
    if (has) {
#pragma unroll
      for (int sub = 0; sub < 4; ++sub) {
        labm1[sub] = lbp[sub * 16];
#pragma unroll
        for (int reg = 0; reg < 4; ++reg)
          pc1[sub][reg] = pcp[reg][sub * 16];
      }
      lbp += 64;
#pragma unroll
      for (int reg = 0; reg < 4; ++reg) pcp[reg] += 64;
    }

    // PV (same-wave LDS in-order)
    const bf16x8 pa0 = *(const bf16x8*)&u_s.p[w][lr][quad * 8];
    const bf16x8 pa1 = *(const bf16x8*)&u_s.p[w][lr][32 + quad * 8];
    __builtin_amdgcn_s_setprio(1);
#pragma unroll
    for (int sub = 0; sub < 4; ++sub) {
      const bf16x8 vb0 = *(const bf16x8*)&vt_s[sub * 16 + lr][quad * 8];
      const bf16x8 vb1 = *(const bf16x8*)&vt_s[sub * 16 + lr][32 + quad * 8];
      oacc[sub] = __builtin_amdgcn_mfma_f32_16x16x32_bf16(pa0, vb0, oacc[sub], 0, 0, 0);
      oacc[sub] = __builtin_amdgcn_mfma_f32_16x16x32_bf16(pa1, vb1, oacc[sub], 0, 0, 0);
    }
    __builtin_amdgcn_s_setprio(0);

    // gather next tile's acg (LDS latency hides under barrier + next QK)
    if (has) {
#pragma unroll
      for (int sub = 0; sub < 4; ++sub)
#pragma unroll
        for (int reg = 0; reg < 4; ++reg)
          acg[sub][reg] = ac_s[row_l + reg][labm1[sub]];
    }

    __syncthreads();             // all waves done reading k_s/vt_s
    if (has) {
      *(uint4*)&k_s[sr2][so2] = ka0; *(uint4*)&k_s[sr2][so2 + 8] = ka1;
      *(uint4*)&vt_s[sr2][so2] = va0; *(uint4*)&vt_s[sr2][so2 + 8] = va1;
    }
    __syncthreads();             // next tile visible
  }

  // epilogue: partial sums (no normalization; combine_k divides)
#pragma unroll
  for (int reg = 0; reg < 4; ++reg) {
    float l = lrow[reg];
    l += __shfl_xor(l, 1); l += __shfl_xor(l, 2);
    l += __shfl_xor(l, 4); l += __shfl_xor(l, 8);
    const int row = n0 + row_l + reg;
    const long long obase = (long long)part * 2097152 + ((long long)(b * Nv + row)) * Cv + h * HDv;
#pragma unroll
    for (int sub = 0; sub < 4; ++sub)
      opart[obase + sub * 16 + lr] = oacc[sub][reg];
    if (lr == 0)
      lpart[part * 32768 + (b * 4 + h) * 4096 + row] = l;
  }
}

// ---------------------------------------------------------------------------
// Combine split-m partials: aob = (o0+o1)/(l0+l1), bf16
// ---------------------------------------------------------------------------
__global__ __launch_bounds__(256) void combine_k(
    const float* __restrict__ op, const float* __restrict__ lp,
    unsigned short* __restrict__ aob)
{
  const long long i4 = ((long long)blockIdx.x * 256 + threadIdx.x) * 4;
  const int c = (int)(i4 & 255), n = (int)((i4 >> 8) & 4095), b = (int)(i4 >> 20);
  const int h = c >> 6;
  const float l = lp[(b * 4 + h) * 4096 + n] + lp[32768 + (b * 4 + h) * 4096 + n];
  const float inv = 1.f / l;
  const float4 a = *(const float4*)&op[i4];
  const float4 d = *(const float4*)&op[2097152 + i4];
  uint2 pk;
  pk.x = cvt_pk_bf16((a.x + d.x) * inv, (a.y + d.y) * inv);
  pk.y = cvt_pk_bf16((a.z + d.z) * inv, (a.w + d.w) * inv);
  *(uint2*)&aob[i4] = pk;
}

// ---------------------------------------------------------------------------
extern "C" void kernel_launch(void* const* d_in, const int* in_sizes, int n_in,
                              void* d_out, int out_size, void* d_ws, size_t ws_size,
                              hipStream_t stream)
{
  const float* q_img = (const float*)d_in[0];
  const float* k_img = (const float*)d_in[1];
  const float* v_img = (const float*)d_in[2];
  const int* labels  = (const int*)d_in[3];
  const float* pc    = (const float*)d_in[4];
  const float* Wq  = (const float*)d_in[5];  const float* bq  = (const float*)d_in[6];
  const float* Wk  = (const float*)d_in[7];  const float* bk  = (const float*)d_in[8];
  const float* Wv  = (const float*)d_in[9];  const float* bv  = (const float*)d_in[10];
  const float* W11 = (const float*)d_in[11]; const float* b11 = (const float*)d_in[12];
  const float* W12 = (const float*)d_in[13]; const float* b12 = (const float*)d_in[14];
  const float* W21 = (const float*)d_in[15]; const float* b21 = (const float*)d_in[16];
  const float* W22 = (const float*)d_in[17]; const float* b22 = (const float*)d_in[18];
  float* outp = (float*)d_out;

  const long long SZ = (long long)Bv * Nv * Cv;     // 2,097,152
  // fp32 region (~32.3 MB)
  float* ws    = (float*)d_ws;
  float* vpp   = ws;                       // v proj fp32
  float* rs1   = vpp + SZ;                 // MLP1 out fp32
  float* opart = rs1 + SZ;                 // attn partials [2][B][N][C]
  float* lpart = opart + 2 * SZ;           // [2][B][NH][N]
  float* cent  = lpart + 65536;            // [B][K][C]
  float* cnts  = cent + Bv * Kv * Cv;      // [B][K]
  // bf16 region (~25.4 MB)
  unsigned short* wt   = (unsigned short*)(cnts + Bv * Kv);
  unsigned short* qbf  = wt + 720896;      // [B][N][C] pre-scaled 0.125*log2e
  unsigned short* kbf  = qbf + SZ;
  unsigned short* vtb  = kbf + SZ;         // [B][C][N]
  unsigned short* aob  = vtb + SZ;         // attn out bf16
  unsigned short* h1b  = aob + SZ;         // MLP hidden [2N][2C]
  unsigned short* imgT = aob;              // overlay (dead after proj_k)

  // prep
  imgt_k<<<dim3(Nv / 32, Cv / 32, 6), dim3(32, 8), 0, stream>>>(q_img, k_img, v_img, imgT);
  WP wp = {{Wq, Wk, Wv, W11, W12, W21, W22}};
  wt_k<<<dim3(16, 16, 7), dim3(32, 8), 0, stream>>>(wp, wt);

  // fused q/k/v projections (64x64 tiles, 1536 blocks = 6/CU)
  proj64_k<<<dim3(64, 4, 6), 256, 0, stream>>>(imgT, wt, bq, bk, bv, qbf, kbf, vpp, vtb);

  // cluster centers
  zero_k<<<dim3(33), 256, 0, stream>>>(cent, Bv * Kv * Cv + Bv * Kv);
  center_accum<<<dim3(Bv * Kv * 8), 256, 0, stream>>>(kbf, labels, cent, cnts);
  center_norm<<<dim3(Bv * Kv * Cv / 256), 256, 0, stream>>>(cent, cnts);

  // attention (split-m x2) + combine
  attn_k<<<dim3(1024), 256, 0, stream>>>(qbf, kbf, vtb, cent, labels, pc, opart, lpart);
  combine_k<<<dim3(2048), 256, 0, stream>>>(opart, lpart, aob);

  // MLP1: h1 = leaky(aob@W11+b11); rs1 = vpp + h1@W12+b12
  mm64_k<true, 1, 0, 1><<<dim3(128, 8), 256, 0, stream>>>(
      aob, wt + 196608, b11, nullptr, nullptr, h1b, 2 * Nv, 2 * Cv, Cv);
  mm64_k<true, 0, 1, 0><<<dim3(128, 4), 256, 0, stream>>>(
      h1b, wt + 327680, b12, vpp, rs1, nullptr, 2 * Nv, Cv, 2 * Cv);

  // MLP2: h2 = leaky(rs1@W21+b21); out = rs1 + h2@W22+b22 -> [B][C][H][W]
  mm64_k<false, 1, 0, 1><<<dim3(128, 8), 256, 0, stream>>>(
      rs1, wt + 458752, b21, nullptr, nullptr, h1b, 2 * Nv, 2 * Cv, Cv);
  mm64_k<true, 0, 1, 4><<<dim3(128, 4), 256, 0, stream>>>(
      h1b, wt + 589824, b22, rs1, outp, nullptr, 2 * Nv, Cv, 2 * Cv);
}

// Round 4
// 403.555 us; speedup vs baseline: 1.5882x; 1.0085x over previous
//
#include <hip/hip_runtime.h>
#include <stdint.h>

#define Bv 2
#define Cv 256
#define Nv 4096
#define NHv 4
#define HDv 64
#define Kv 16

// R10: attn = R8 body (direct addressing, measured 119.5) + ds_bpermute ac
// gather (replaces conflicting LDS gather: acv[reg] register-resident row
// values, cross-lane pull by label). proj64/mm64 pipelines kept from R9.
// MLP1b dual-writes rs1 fp32+bf16 (into dead aob); mm2a reads bf16 A.

typedef __attribute__((ext_vector_type(8))) short bf16x8;
typedef __attribute__((ext_vector_type(4))) float f32x4;

__device__ __forceinline__ float bf2f(unsigned short u) {
  union { unsigned int i; float f; } x; x.i = ((unsigned int)u) << 16; return x.f;
}
__device__ __forceinline__ unsigned short f2bf(float f) {
  union { float f; unsigned int i; } x; x.f = f;
  unsigned int r = x.i + 0x7FFF + ((x.i >> 16) & 1);   // RNE
  return (unsigned short)(r >> 16);
}
__device__ __forceinline__ unsigned int cvt_pk_bf16(float lo, float hi) {
  unsigned int r;
  asm("v_cvt_pk_bf16_f32 %0, %1, %2" : "=v"(r) : "v"(lo), "v"(hi));
  return r;
}
__device__ __forceinline__ float exp2_raw(float x) {
  float r;
  asm("v_exp_f32 %0, %1" : "=v"(r) : "v"(x));
  return r;
}
__device__ __forceinline__ float bperm_f(int idx_bytes, float v) {
  return __int_as_float(__builtin_amdgcn_ds_bpermute(idx_bytes, __float_as_int(v)));
}

// ---------------------------------------------------------------------------
// Prep 1: img [b][c][n] fp32 -> imgT [z][n][c] bf16  (z = img*2 + b, z<6)
// ---------------------------------------------------------------------------
__global__ __launch_bounds__(256) void imgt_k(
    const float* __restrict__ qi, const float* __restrict__ ki,
    const float* __restrict__ vi, unsigned short* __restrict__ dst)
{
  const int z = blockIdx.z;
  const float* src = (z < 2 ? qi : (z < 4 ? ki : vi)) + (long long)(z & 1) * Cv * Nv;
  unsigned short* out = dst + (long long)z * Nv * Cv;
  __shared__ float t[32][33];
  const int x = threadIdx.x, y = threadIdx.y;
  const int n0 = blockIdx.x * 32, c0 = blockIdx.y * 32;
  for (int i = y; i < 32; i += 8)
    t[i][x] = src[(long long)(c0 + i) * Nv + n0 + x];
  __syncthreads();
  for (int i = y; i < 32; i += 8)
    out[(long long)(n0 + i) * Cv + c0 + x] = f2bf(t[x][i]);
}

// ---------------------------------------------------------------------------
// Prep 2: W [k][n] fp32 -> Wt [n][k] bf16, 7 weights packed into one buffer
// ---------------------------------------------------------------------------
struct WP { const float* p[7]; };

__global__ __launch_bounds__(256) void wt_k(WP wp, unsigned short* __restrict__ dst)
{
  const int z = blockIdx.z;
  const int KD[7] = {256, 256, 256, 256, 512, 256, 512};
  const int ND[7] = {256, 256, 256, 512, 256, 512, 256};
  const long long OFF[7] = {0, 65536, 131072, 196608, 327680, 458752, 589824};
  const int Kw = KD[z], Nw = ND[z];
  const int nb = blockIdx.x * 32, kb2 = blockIdx.y * 32;
  if (nb >= Nw || kb2 >= Kw) return;
  __shared__ float t[32][33];
  const int x = threadIdx.x, y = threadIdx.y;
  const float* src = wp.p[z];
  for (int i = y; i < 32; i += 8)
    t[i][x] = src[(long long)(kb2 + i) * Nw + nb + x];
  __syncthreads();
  for (int i = y; i < 32; i += 8)
    dst[OFF[z] + (long long)(nb + i) * Kw + kb2 + x] = f2bf(t[x][i]);
}

// ---------------------------------------------------------------------------
// Fused q/k/v projection, 64x64 tiles (z = proj*2 + b, z<6). 1536 blocks.
// Register-prefetch K pipeline. Epilogue per proj: q->qbf(*0.125*log2e),
// k->kbf, v->vpp fp32 + vtb bf16 transposed [c][n].
// ---------------------------------------------------------------------------
__global__ __launch_bounds__(256) void proj64_k(
    const unsigned short* __restrict__ imgT, const unsigned short* __restrict__ wt,
    const float* __restrict__ bq, const float* __restrict__ bk, const float* __restrict__ bv,
    unsigned short* __restrict__ qbf, unsigned short* __restrict__ kbf,
    float* __restrict__ vpp, unsigned short* __restrict__ vtb)
{
  __shared__ __align__(16) unsigned short As[64][72];
  __shared__ __align__(16) unsigned short Bs[64][72];
  const int tid = threadIdx.x;
  const int w = tid >> 6, lane = tid & 63;
  const int lr = lane & 15, quad = lane >> 4;
  const int m0 = blockIdx.x * 64, n0 = blockIdx.y * 64;
  const int z = blockIdx.z, zz = z >> 1, bb = z & 1;
  const int wm = (w >> 1) * 32, wn = (w & 1) * 32;
  const int sr = tid >> 2, sh = (tid & 3) * 16;
  const long long NvCv = (long long)Nv * Cv;

  const float* bias = zz == 0 ? bq : (zz == 1 ? bk : bv);
  const unsigned short* Ab0 = imgT + (long long)z * NvCv + (long long)(m0 + sr) * Cv + sh;
  const unsigned short* Bb0 = wt + (long long)zz * 65536 + (long long)(n0 + sr) * Cv + sh;

  f32x4 acc[2][2];
#pragma unroll
  for (int i = 0; i < 2; ++i)
#pragma unroll
    for (int j = 0; j < 2; ++j) acc[i][j] = (f32x4){0.f, 0.f, 0.f, 0.f};

  uint4 rA0 = *(const uint4*)Ab0, rA1 = *(const uint4*)(Ab0 + 8);
  uint4 rB0 = *(const uint4*)Bb0, rB1 = *(const uint4*)(Bb0 + 8);

  for (int k0 = 0; k0 < Cv; k0 += 64) {
    *(uint4*)&As[sr][sh] = rA0; *(uint4*)&As[sr][sh + 8] = rA1;
    *(uint4*)&Bs[sr][sh] = rB0; *(uint4*)&Bs[sr][sh + 8] = rB1;
    __syncthreads();
    if (k0 + 64 < Cv) {
      rA0 = *(const uint4*)(Ab0 + k0 + 64); rA1 = *(const uint4*)(Ab0 + k0 + 72);
      rB0 = *(const uint4*)(Bb0 + k0 + 64); rB1 = *(const uint4*)(Bb0 + k0 + 72);
    }
#pragma unroll
    for (int ks = 0; ks < 2; ++ks) {
      bf16x8 af[2], bfr[2];
#pragma unroll
      for (int i = 0; i < 2; ++i)
        af[i] = *(const bf16x8*)&As[wm + i * 16 + lr][ks * 32 + quad * 8];
#pragma unroll
      for (int j = 0; j < 2; ++j)
        bfr[j] = *(const bf16x8*)&Bs[wn + j * 16 + lr][ks * 32 + quad * 8];
#pragma unroll
      for (int i = 0; i < 2; ++i)
#pragma unroll
        for (int j = 0; j < 2; ++j)
          acc[i][j] = __builtin_amdgcn_mfma_f32_16x16x32_bf16(af[i], bfr[j], acc[i][j], 0, 0, 0);
    }
    __syncthreads();
  }

#pragma unroll
  for (int j = 0; j < 2; ++j) {
    const int col = n0 + wn + j * 16 + lr;
    const float bvv = bias[col];
#pragma unroll
    for (int i = 0; i < 2; ++i) {
      const int mb = m0 + wm + i * 16 + quad * 4;
      float r[4];
#pragma unroll
      for (int reg = 0; reg < 4; ++reg) r[reg] = acc[i][j][reg] + bvv;
      const long long ob = (long long)bb * NvCv;
      if (zz == 0) {
        // 0.125 (1/SCALE) * log2(e): softmax runs in exp2 domain
#pragma unroll
        for (int reg = 0; reg < 4; ++reg)
          qbf[ob + (long long)(mb + reg) * Cv + col] = f2bf(r[reg] * 0.18033688f);
      } else if (zz == 1) {
#pragma unroll
        for (int reg = 0; reg < 4; ++reg)
          kbf[ob + (long long)(mb + reg) * Cv + col] = f2bf(r[reg]);
      } else {
#pragma unroll
        for (int reg = 0; reg < 4; ++reg)
          vpp[ob + (long long)(mb + reg) * Cv + col] = r[reg];
        uint2 pk;
        pk.x = cvt_pk_bf16(r[0], r[1]);
        pk.y = cvt_pk_bf16(r[2], r[3]);
        *(uint2*)&vtb[ob + (long long)col * Nv + mb] = pk;
      }
    }
  }
}

// ---------------------------------------------------------------------------
// 64x64-tile bf16 MFMA GEMM for the MLPs, register-prefetch K pipeline.
// OM: 0 fp32 [m][n]; 1 bf16 [m][n]; 2 fp32+bf16 dual; 4 fp32 -> [B][C][N].
// ---------------------------------------------------------------------------
template<bool ABF16, int ACT, int RES, int OM>
__global__ __launch_bounds__(256) void mm64_k(
    const void* __restrict__ A, const unsigned short* __restrict__ Bt,
    const float* __restrict__ bias, const float* __restrict__ Res,
    float* __restrict__ outF, unsigned short* __restrict__ outB,
    int M, int Nn, int Kd)
{
  __shared__ __align__(16) unsigned short As[64][72];
  __shared__ __align__(16) unsigned short Bs[64][72];
  const int tid = threadIdx.x;
  const int w = tid >> 6, lane = tid & 63;
  const int lr = lane & 15, quad = lane >> 4;
  const int m0 = blockIdx.x * 64, n0 = blockIdx.y * 64;
  const int wm = (w >> 1) * 32, wn = (w & 1) * 32;
  const int sr = tid >> 2, sh = (tid & 3) * 16;

  f32x4 acc[2][2];
#pragma unroll
  for (int i = 0; i < 2; ++i)
#pragma unroll
    for (int j = 0; j < 2; ++j) acc[i][j] = (f32x4){0.f, 0.f, 0.f, 0.f};

  const long long abase = (long long)(m0 + sr) * Kd + sh;
  const unsigned short* Bb = Bt + (long long)(n0 + sr) * Kd + sh;

  uint4 rA0, rA1, rB0, rB1;
  float4 fA[4];
  if (ABF16) {
    const unsigned short* Ab = (const unsigned short*)A + abase;
    rA0 = *(const uint4*)Ab; rA1 = *(const uint4*)(Ab + 8);
  } else {
    const float* Af = (const float*)A + abase;
    fA[0] = *(const float4*)Af;      fA[1] = *(const float4*)(Af + 4);
    fA[2] = *(const float4*)(Af + 8); fA[3] = *(const float4*)(Af + 12);
  }
  rB0 = *(const uint4*)Bb; rB1 = *(const uint4*)(Bb + 8);

  for (int k0 = 0; k0 < Kd; k0 += 64) {
    if (ABF16) {
      *(uint4*)&As[sr][sh] = rA0; *(uint4*)&As[sr][sh + 8] = rA1;
    } else {
#pragma unroll
      for (int t = 0; t < 2; ++t) {
        uint4 pk;
        pk.x = cvt_pk_bf16(fA[t * 2].x, fA[t * 2].y);
        pk.y = cvt_pk_bf16(fA[t * 2].z, fA[t * 2].w);
        pk.z = cvt_pk_bf16(fA[t * 2 + 1].x, fA[t * 2 + 1].y);
        pk.w = cvt_pk_bf16(fA[t * 2 + 1].z, fA[t * 2 + 1].w);
        *(uint4*)&As[sr][sh + t * 8] = pk;
      }
    }
    *(uint4*)&Bs[sr][sh] = rB0; *(uint4*)&Bs[sr][sh + 8] = rB1;
    __syncthreads();
    if (k0 + 64 < Kd) {
      if (ABF16) {
        const unsigned short* Ab = (const unsigned short*)A + abase + k0 + 64;
        rA0 = *(const uint4*)Ab; rA1 = *(const uint4*)(Ab + 8);
      } else {
        const float* Af = (const float*)A + abase + k0 + 64;
        fA[0] = *(const float4*)Af;      fA[1] = *(const float4*)(Af + 4);
        fA[2] = *(const float4*)(Af + 8); fA[3] = *(const float4*)(Af + 12);
      }
      rB0 = *(const uint4*)(Bb + k0 + 64); rB1 = *(const uint4*)(Bb + k0 + 72);
    }
#pragma unroll
    for (int ks = 0; ks < 2; ++ks) {
      bf16x8 af[2], bfr[2];
#pragma unroll
      for (int i = 0; i < 2; ++i)
        af[i] = *(const bf16x8*)&As[wm + i * 16 + lr][ks * 32 + quad * 8];
#pragma unroll
      for (int j = 0; j < 2; ++j)
        bfr[j] = *(const bf16x8*)&Bs[wn + j * 16 + lr][ks * 32 + quad * 8];
#pragma unroll
      for (int i = 0; i < 2; ++i)
#pragma unroll
        for (int j = 0; j < 2; ++j)
          acc[i][j] = __builtin_amdgcn_mfma_f32_16x16x32_bf16(af[i], bfr[j], acc[i][j], 0, 0, 0);
    }
    __syncthreads();
  }

#pragma unroll
  for (int j = 0; j < 2; ++j) {
    const int col = n0 + wn + j * 16 + lr;
    const float bv = bias[col];
#pragma unroll
    for (int i = 0; i < 2; ++i) {
      const int mb = m0 + wm + i * 16 + quad * 4;
      float r[4];
#pragma unroll
      for (int reg = 0; reg < 4; ++reg) {
        float v = acc[i][j][reg] + bv;
        if (ACT) v = v > 0.f ? v : 0.01f * v;
        if (RES) v += Res[(long long)(mb + reg) * Nn + col];
        r[reg] = v;
      }
      if (OM == 0) {
#pragma unroll
        for (int reg = 0; reg < 4; ++reg)
          outF[(long long)(mb + reg) * Nn + col] = r[reg];
      } else if (OM == 1) {
#pragma unroll
        for (int reg = 0; reg < 4; ++reg)
          outB[(long long)(mb + reg) * Nn + col] = f2bf(r[reg]);
      } else if (OM == 2) {   // dual: fp32 + bf16 copies of [m][n]
#pragma unroll
        for (int reg = 0; reg < 4; ++reg) {
          outF[(long long)(mb + reg) * Nn + col] = r[reg];
          outB[(long long)(mb + reg) * Nn + col] = f2bf(r[reg]);
        }
      } else {  // OM == 4: fp32 [B][C][N], m flattened over (b,n)
        const float4 st = {r[0], r[1], r[2], r[3]};
        *(float4*)&outF[((long long)((mb >> 12) * Cv + col)) * Nv + (mb & 4095)] = st;
      }
    }
  }
}

// ---------------------------------------------------------------------------
// Cluster centers
// ---------------------------------------------------------------------------
__global__ __launch_bounds__(256) void zero_k(float* p, int n)
{
  const int i = blockIdx.x * 256 + threadIdx.x;
  if (i < n) p[i] = 0.f;
}

__global__ __launch_bounds__(256) void center_accum(
    const unsigned short* __restrict__ kb, const int* __restrict__ labels,
    float* __restrict__ cent, float* __restrict__ cnts)
{
  __shared__ int lab_s[512];
  const int bx = blockIdx.x;           // Bv*Kv*8 blocks
  const int chunk = bx & 7;
  const int kk = (bx >> 3) & 15;
  const int b = bx >> 7;
  const int c = threadIdx.x;
  const int nbase = chunk * 512;
  for (int i = threadIdx.x; i < 512; i += 256) lab_s[i] = labels[b * Nv + nbase + i];
  __syncthreads();
  float acc = 0.f;
  int cnt = 0;
#pragma unroll 4
  for (int i = 0; i < 512; ++i) {
    if (lab_s[i] == kk) {              // wave-uniform branch on LDS value
      acc += bf2f(kb[(long long)(b * Nv + nbase + i) * Cv + c]);
      ++cnt;
    }
  }
  atomicAdd(&cent[(b * Kv + kk) * Cv + c], acc);
  if (c == 0) atomicAdd(&cnts[b * Kv + kk], (float)cnt);
}

__global__ __launch_bounds__(256) void center_norm(float* cent, const float* cnts)
{
  const int i = blockIdx.x * 256 + threadIdx.x;  // Bv*Kv*Cv
  cent[i] = cent[i] / (cnts[i >> 8] + 1e-6f);
}

// ---------------------------------------------------------------------------
// MFMA flash attention, split-m x2 (R8 structure + bpermute ac gather).
// Block = (part, b, h, qtile). 40,704B LDS -> 4 blocks/CU.
// p = exp2(s), no shift (q carries 0.125*log2e). cvt_pk P pack.
// acv[reg] holds ac row values across lanes lr; per-element gather is a
// ds_bpermute from lane (quad*16 + label) -- conflict-free, no addr math.
// Partials: opart[part][b][n][c] fp32, lpart[part][b][h][n].
// ---------------------------------------------------------------------------
union PSCS {
  unsigned short p[4][16][68];   // P tiles (per wave), used in main loop
  float c[16][68];               // centers, used only in prologue
};

__global__ __launch_bounds__(256) void attn_k(
    const unsigned short* __restrict__ qb, const unsigned short* __restrict__ kb,
    const unsigned short* __restrict__ vtb, const float* __restrict__ cent,
    const int* __restrict__ labels, const float* __restrict__ pc,
    float* __restrict__ opart, float* __restrict__ lpart)
{
  __shared__ __align__(16) unsigned short q_s[64][72];
  __shared__ __align__(16) unsigned short k_s[64][72];
  __shared__ __align__(16) unsigned short vt_s[64][72];
  __shared__ __align__(16) PSCS u_s;
  __shared__ float ac_s[64][17];

  const int tid = threadIdx.x;
  const int lane = tid & 63, w = tid >> 6;
  const int lr = lane & 15, quad = lane >> 4;
  const int bx = blockIdx.x;
  const int qt = bx & 63, h = (bx >> 6) & 3, b = (bx >> 8) & 1;
  const int part = bx >> 9;
  const int n0 = qt * 64;
  const int mbase = part * 2048;
  const int sr2 = tid >> 2, so2 = (tid & 3) * 16;
  const int row_l = w * 16 + quad * 4;
  const long long pcb = (long long)b * Nv * Nv;

  // ---- prologue: stage q + centers
  {
    const unsigned short* src = qb + ((long long)(b * Nv + n0 + sr2)) * Cv + h * HDv + so2;
    *(uint4*)&q_s[sr2][so2] = *(const uint4*)src;
    *(uint4*)&q_s[sr2][so2 + 8] = *(const uint4*)(src + 8);
  }
  for (int idx = tid; idx < Kv * HDv; idx += 256)
    u_s.c[idx >> 6][idx & 63] = cent[((long long)(b * Kv + (idx >> 6))) * Cv + h * HDv + (idx & 63)];

  // issue tile-0 k/v + pc + labm loads while the block syncs
  uint4 ka0, ka1, va0, va1;
  float pc1[4][4];
  int labm1[4], labq[4];
  {
    const long long ks = ((long long)(b * Nv + mbase + sr2)) * Cv + h * HDv + so2;
    ka0 = *(const uint4*)(kb + ks); ka1 = *(const uint4*)(kb + ks + 8);
    const long long vs = ((long long)(b * Cv + h * HDv + sr2)) * Nv + mbase + so2;
    va0 = *(const uint4*)(vtb + vs); va1 = *(const uint4*)(vtb + vs + 8);
  }
#pragma unroll
  for (int sub = 0; sub < 4; ++sub) {
    labm1[sub] = labels[b * Nv + mbase + sub * 16 + lr];
#pragma unroll
    for (int reg = 0; reg < 4; ++reg)
      pc1[sub][reg] = pc[pcb + (long long)(n0 + row_l + reg) * Nv + mbase + sub * 16 + lr];
  }
#pragma unroll
  for (int reg = 0; reg < 4; ++reg) labq[reg] = labels[b * Nv + n0 + row_l + reg];

  __syncthreads();               // q_s, u_s.c visible
  // ac_s[r][k] = (q_r scaled) . center_k
  for (int idx = tid; idx < 64 * Kv; idx += 256) {
    const int r = idx >> 4, kk = idx & 15;
    float s = 0.f;
#pragma unroll
    for (int d = 0; d < HDv; ++d) s += bf2f(q_s[r][d]) * u_s.c[kk][d];
    ac_s[r][kk] = s;
  }
  const bf16x8 qa0 = *(const bf16x8*)&q_s[w * 16 + lr][quad * 8];
  const bf16x8 qa1 = *(const bf16x8*)&q_s[w * 16 + lr][32 + quad * 8];
  __syncthreads();               // ac_s visible; all waves done with u_s.c

  // acv[reg]: lane (lr,quad) holds ac_s[w*16+quad*4+reg][lr] -- the wave's 16
  // row-vectors distributed across lanes; gathers become cross-lane pulls.
  float acv[4];
#pragma unroll
  for (int reg = 0; reg < 4; ++reg) acv[reg] = ac_s[w * 16 + quad * 4 + reg][lr];

  // tile-0 acg gather via bpermute (src lane = quad*16 + label)
  float acg[4][4];
#pragma unroll
  for (int sub = 0; sub < 4; ++sub) {
    const int bidx = (quad << 6) + (labm1[sub] << 2);
#pragma unroll
    for (int reg = 0; reg < 4; ++reg)
      acg[sub][reg] = bperm_f(bidx, acv[reg]);
  }

  // stage tile 0 from regs
  *(uint4*)&k_s[sr2][so2] = ka0; *(uint4*)&k_s[sr2][so2 + 8] = ka1;
  *(uint4*)&vt_s[sr2][so2] = va0; *(uint4*)&vt_s[sr2][so2 + 8] = va1;
  __syncthreads();               // tile 0 visible

  f32x4 oacc[4];
#pragma unroll
  for (int s2 = 0; s2 < 4; ++s2) oacc[s2] = (f32x4){0.f, 0.f, 0.f, 0.f};
  float lrow[4] = {0.f, 0.f, 0.f, 0.f};

  for (int t = 0; t < 32; ++t) {
    const int m0 = mbase + t * 64;
    const bool has = (t < 31);

    // prefetch next tile k/v into regs (hidden behind this tile's compute)
    if (has) {
      const long long ks = ((long long)(b * Nv + m0 + 64 + sr2)) * Cv + h * HDv + so2;
      ka0 = *(const uint4*)(kb + ks); ka1 = *(const uint4*)(kb + ks + 8);
      const long long vs = ((long long)(b * Cv + h * HDv + sr2)) * Nv + m0 + 64 + so2;
      va0 = *(const uint4*)(vtb + vs); va1 = *(const uint4*)(vtb + vs + 8);
    }

    // QK^T
    f32x4 sacc[4];
    __builtin_amdgcn_s_setprio(1);
#pragma unroll
    for (int sub = 0; sub < 4; ++sub) {
      const bf16x8 kb0 = *(const bf16x8*)&k_s[sub * 16 + lr][quad * 8];
      const bf16x8 kb1 = *(const bf16x8*)&k_s[sub * 16 + lr][32 + quad * 8];
      f32x4 s = (f32x4){0.f, 0.f, 0.f, 0.f};
      s = __builtin_amdgcn_mfma_f32_16x16x32_bf16(qa0, kb0, s, 0, 0, 0);
      s = __builtin_amdgcn_mfma_f32_16x16x32_bf16(qa1, kb1, s, 0, 0, 0);
      sacc[sub] = s;
    }
    __builtin_amdgcn_s_setprio(0);

    // adaptive select + exp2(s), cvt_pk P pack, accumulate denominator
#pragma unroll
    for (int sub = 0; sub < 4; ++sub) {
      float p4[4];
#pragma unroll
      for (int reg = 0; reg < 4; ++reg) {
        const float s = (labm1[sub] == labq[reg]) ? sacc[sub][reg]
                                                  : acg[sub][reg] * pc1[sub][reg];
        const float p = exp2_raw(s);
        lrow[reg] += p;
        p4[reg] = p;
      }
      const unsigned int pk01 = cvt_pk_bf16(p4[0], p4[1]);
      const unsigned int pk23 = cvt_pk_bf16(p4[2], p4[3]);
      unsigned short* pp = &u_s.p[w][quad * 4][sub * 16 + lr];
      pp[0]   = (unsigned short)pk01;
      pp[68]  = (unsigned short)(pk01 >> 16);
      pp[136] = (unsigned short)pk23;
      pp[204] = (unsigned short)(pk23 >> 16);
    }

    // pc/labm consumed -> issue next tile's loads (covers PV + barriers + QK)
    if (has) {
#pragma unroll
      for (int sub = 0; sub < 4; ++sub) {
        labm1[sub] = labels[b * Nv + m0 + 64 + sub * 16 + lr];
#pragma unroll
        for (int reg = 0; reg < 4; ++reg)
          pc1[sub][reg] = pc[pcb + (long long)(n0 + row_l + reg) * Nv + m0 + 64 + sub * 16 + lr];
      }
    }

    // PV (same-wave LDS in-order)
    const bf16x8 pa0 = *(const bf16x8*)&u_s.p[w][lr][quad * 8];
    const bf16x8 pa1 = *(const bf16x8*)&u_s.p[w][lr][32 + quad * 8];
    __builtin_amdgcn_s_setprio(1);
#pragma unroll
    for (int sub = 0; sub < 4; ++sub) {
      const bf16x8 vb0 = *(const bf16x8*)&vt_s[sub * 16 + lr][quad * 8];
      const bf16x8 vb1 = *(const bf16x8*)&vt_s[sub * 16 + lr][32 + quad * 8];
      oacc[sub] = __builtin_amdgcn_mfma_f32_16x16x32_bf16(pa0, vb0, oacc[sub], 0, 0, 0);
      oacc[sub] = __builtin_amdgcn_mfma_f32_16x16x32_bf16(pa1, vb1, oacc[sub], 0, 0, 0);
    }
    __builtin_amdgcn_s_setprio(0);

    // gather next tile's acg via bpermute (labm1 in flight; latency hides
    // under the barrier + staging + next QK)
    if (has) {
#pragma unroll
      for (int sub = 0; sub < 4; ++sub) {
        const int bidx = (quad << 6) + (labm1[sub] << 2);
#pragma unroll
        for (int reg = 0; reg < 4; ++reg)
          acg[sub][reg] = bperm_f(bidx, acv[reg]);
      }
    }

    __syncthreads();             // all waves done reading k_s/vt_s
    if (has) {
      *(uint4*)&k_s[sr2][so2] = ka0; *(uint4*)&k_s[sr2][so2 + 8] = ka1;
      *(uint4*)&vt_s[sr2][so2] = va0; *(uint4*)&vt_s[sr2][so2 + 8] = va1;
    }
    __syncthreads();             // next tile visible
  }

  // epilogue: partial sums (no normalization; combine_k divides)
#pragma unroll
  for (int reg = 0; reg < 4; ++reg) {
    float l = lrow[reg];
    l += __shfl_xor(l, 1); l += __shfl_xor(l, 2);
    l += __shfl_xor(l, 4); l += __shfl_xor(l, 8);
    const int row = n0 + row_l + reg;
    const long long obase = (long long)part * 2097152 + ((long long)(b * Nv + row)) * Cv + h * HDv;
#pragma unroll
    for (int sub = 0; sub < 4; ++sub)
      opart[obase + sub * 16 + lr] = oacc[sub][reg];
    if (lr == 0)
      lpart[part * 32768 + (b * 4 + h) * 4096 + row] = l;
  }
}

// ---------------------------------------------------------------------------
// Combine split-m partials: aob = (o0+o1)/(l0+l1), bf16
// ---------------------------------------------------------------------------
__global__ __launch_bounds__(256) void combine_k(
    const float* __restrict__ op, const float* __restrict__ lp,
    unsigned short* __restrict__ aob)
{
  const long long i4 = ((long long)blockIdx.x * 256 + threadIdx.x) * 4;
  const int c = (int)(i4 & 255), n = (int)((i4 >> 8) & 4095), b = (int)(i4 >> 20);
  const int h = c >> 6;
  const float l = lp[(b * 4 + h) * 4096 + n] + lp[32768 + (b * 4 + h) * 4096 + n];
  const float inv = 1.f / l;
  const float4 a = *(const float4*)&op[i4];
  const float4 d = *(const float4*)&op[2097152 + i4];
  uint2 pk;
  pk.x = cvt_pk_bf16((a.x + d.x) * inv, (a.y + d.y) * inv);
  pk.y = cvt_pk_bf16((a.z + d.z) * inv, (a.w + d.w) * inv);
  *(uint2*)&aob[i4] = pk;
}

// ---------------------------------------------------------------------------
extern "C" void kernel_launch(void* const* d_in, const int* in_sizes, int n_in,
                              void* d_out, int out_size, void* d_ws, size_t ws_size,
                              hipStream_t stream)
{
  const float* q_img = (const float*)d_in[0];
  const float* k_img = (const float*)d_in[1];
  const float* v_img = (const float*)d_in[2];
  const int* labels  = (const int*)d_in[3];
  const float* pc    = (const float*)d_in[4];
  const float* Wq  = (const float*)d_in[5];  const float* bq  = (const float*)d_in[6];
  const float* Wk  = (const float*)d_in[7];  const float* bk  = (const float*)d_in[8];
  const float* Wv  = (const float*)d_in[9];  const float* bv  = (const float*)d_in[10];
  const float* W11 = (const float*)d_in[11]; const float* b11 = (const float*)d_in[12];
  const float* W12 = (const float*)d_in[13]; const float* b12 = (const float*)d_in[14];
  const float* W21 = (const float*)d_in[15]; const float* b21 = (const float*)d_in[16];
  const float* W22 = (const float*)d_in[17]; const float* b22 = (const float*)d_in[18];
  float* outp = (float*)d_out;

  const long long SZ = (long long)Bv * Nv * Cv;     // 2,097,152
  // fp32 region (~32.3 MB)
  float* ws    = (float*)d_ws;
  float* vpp   = ws;                       // v proj fp32
  float* rs1   = vpp + SZ;                 // MLP1 out fp32
  float* opart = rs1 + SZ;                 // attn partials [2][B][N][C]
  float* lpart = opart + 2 * SZ;           // [2][B][NH][N]
  float* cent  = lpart + 65536;            // [B][K][C]
  float* cnts  = cent + Bv * Kv * Cv;      // [B][K]
  // bf16 region (~25.4 MB)
  unsigned short* wt   = (unsigned short*)(cnts + Bv * Kv);
  unsigned short* qbf  = wt + 720896;      // [B][N][C] pre-scaled 0.125*log2e
  unsigned short* kbf  = qbf + SZ;
  unsigned short* vtb  = kbf + SZ;         // [B][C][N]
  unsigned short* aob  = vtb + SZ;         // attn out bf16; later rs1-bf16
  unsigned short* h1b  = aob + SZ;         // MLP hidden [2N][2C]
  unsigned short* imgT = aob;              // overlay (dead after proj)

  // prep
  imgt_k<<<dim3(Nv / 32, Cv / 32, 6), dim3(32, 8), 0, stream>>>(q_img, k_img, v_img, imgT);
  WP wp = {{Wq, Wk, Wv, W11, W12, W21, W22}};
  wt_k<<<dim3(16, 16, 7), dim3(32, 8), 0, stream>>>(wp, wt);

  // fused q/k/v projections (64x64 tiles, 1536 blocks = 6/CU)
  proj64_k<<<dim3(64, 4, 6), 256, 0, stream>>>(imgT, wt, bq, bk, bv, qbf, kbf, vpp, vtb);

  // cluster centers
  zero_k<<<dim3(33), 256, 0, stream>>>(cent, Bv * Kv * Cv + Bv * Kv);
  center_accum<<<dim3(Bv * Kv * 8), 256, 0, stream>>>(kbf, labels, cent, cnts);
  center_norm<<<dim3(Bv * Kv * Cv / 256), 256, 0, stream>>>(cent, cnts);

  // attention (split-m x2) + combine
  attn_k<<<dim3(1024), 256, 0, stream>>>(qbf, kbf, vtb, cent, labels, pc, opart, lpart);
  combine_k<<<dim3(2048), 256, 0, stream>>>(opart, lpart, aob);

  // MLP1: h1 = leaky(aob@W11+b11); rs1 = vpp + h1@W12+b12 (fp32 + bf16->aob)
  mm64_k<true, 1, 0, 1><<<dim3(128, 8), 256, 0, stream>>>(
      aob, wt + 196608, b11, nullptr, nullptr, h1b, 2 * Nv, 2 * Cv, Cv);
  mm64_k<true, 0, 1, 2><<<dim3(128, 4), 256, 0, stream>>>(
      h1b, wt + 327680, b12, vpp, rs1, aob, 2 * Nv, Cv, 2 * Cv);

  // MLP2: h2 = leaky(rs1b@W21+b21); out = rs1 + h2@W22+b22 -> [B][C][H][W]
  mm64_k<true, 1, 0, 1><<<dim3(128, 8), 256, 0, stream>>>(
      aob, wt + 458752, b21, nullptr, nullptr, h1b, 2 * Nv, 2 * Cv, Cv);
  mm64_k<true, 0, 1, 4><<<dim3(128, 4), 256, 0, stream>>>(
      h1b, wt + 589824, b22, rs1, outp, nullptr, 2 * Nv, Cv, 2 * Cv);
}